// Round 14
// baseline (1511.496 us; speedup 1.0000x reference)
//
#include <hip/hip_runtime.h>
#include <math.h>

// ---------------- constants ----------------
#define N_SRC 1024
#define VHW 1024
#define FHW 256
#define MQ 30976            // M-chunk rows (123904/4), = 242 * 128

typedef __attribute__((ext_vector_type(8))) short short8;
typedef __attribute__((ext_vector_type(4))) float f32x4;

#define MFMA_B16(a,b,c) __builtin_amdgcn_mfma_f32_16x16x32_bf16((a),(b),(c),0,0,0)

__device__ __forceinline__ float gelu_f(float x){
  return 0.5f * x * (1.0f + erff(x * 0.70710678118654752440f));
}
__device__ __forceinline__ unsigned short f2bf(float f){
  union { float f; unsigned u; } x; x.f = f;
  unsigned r = x.u + 0x7fffu + ((x.u >> 16) & 1u);
  return (unsigned short)(r >> 16);
}
__device__ __forceinline__ float bf2f(unsigned short h){
  union { unsigned u; float f; } x; x.u = ((unsigned)h) << 16;
  return x.f;
}

// ---------------- gaussian tables ----------------
__global__ void k_gauss(float* __restrict__ gbn, float* __restrict__ gst){
  __shared__ double red[256];
  int t = threadIdx.x;
  {
    double v = 0.0;
    if (t < 121){
      int r = t / 11, c = t % 11;
      double y = -1.0 + 2.0 * (double)r / 10.0;
      double x = -1.0 + 2.0 * (double)c / 10.0;
      v = exp(-(x*x + y*y) / (2.0 * 0.4 * 0.4));
    }
    red[t] = v; __syncthreads();
    for (int s = 128; s > 0; s >>= 1){ if (t < s) red[t] += red[t+s]; __syncthreads(); }
    double sum = red[0];
    __syncthreads();
    if (t < 121) gbn[t] = (float)(v / sum);
    __syncthreads();
  }
  {
    double vals[4]; double loc = 0.0;
    #pragma unroll
    for (int i = 0; i < 4; ++i){
      int j = t + 256*i;
      double v = 0.0;
      if (j < 961){
        int r = j / 31, c = j % 31;
        double y = -1.0 + 2.0 * (double)r / 30.0;
        double x = -1.0 + 2.0 * (double)c / 30.0;
        v = exp(-(x*x + y*y) / (2.0 * 0.4 * 0.4));
      }
      vals[i] = v; loc += v;
    }
    red[t] = loc; __syncthreads();
    for (int s = 128; s > 0; s >>= 1){ if (t < s) red[t] += red[t+s]; __syncthreads(); }
    double sum = red[0];
    __syncthreads();
    #pragma unroll
    for (int i = 0; i < 4; ++i){
      int j = t + 256*i;
      if (j < 961) gst[j] = (float)(vals[i] / sum);
    }
  }
}

// ---------------- weight conversion ----------------
__global__ void k_trans(const float* __restrict__ pw1_w, const float* __restrict__ pw2_w,
                        const float* __restrict__ bn_w,
                        const float* __restrict__ st1_w, const float* __restrict__ st2_w,
                        unsigned short* __restrict__ W1b, unsigned short* __restrict__ W2b,
                        unsigned short* __restrict__ bnWb,
                        unsigned short* __restrict__ Wc1, unsigned short* __restrict__ Wc2){
  int stride = gridDim.x * blockDim.x;
  int i0 = blockIdx.x * blockDim.x + threadIdx.x;
  for (int e = i0; e < 256*1024; e += stride) W1b[e] = f2bf(pw1_w[e]);
  for (int e = i0; e < 256*1024; e += stride) W2b[e] = f2bf(pw2_w[e]);
  for (int e = i0; e < 128*256; e += stride) bnWb[e] = f2bf(bn_w[e]);
  for (int e = i0; e < 64*576; e += stride){
    int co = e / 576, r = e % 576, d = r >> 6, ci = r & 63;
    Wc1[e] = f2bf(st1_w[(co*64 + ci)*9 + d]);
    Wc2[e] = f2bf(st2_w[(co*64 + ci)*9 + d]);
  }
}

// =======================================================================
// st path:
//   k_stg    : wave-coalesced gather vis -> v_win bf16 plane-major [8cg][n*961][8]
//   k_stconv : fused conv1+conv2, granule-major LDS (strides == 2 mod 8 ->
//              conflict-free), 2 co-tiles/wave, 2 blocks/CU
// =======================================================================

__global__ __launch_bounds__(256) void k_stg(
    const float* __restrict__ vis, const float* __restrict__ pos,
    unsigned short* __restrict__ v_win)
{
  int b = blockIdx.x;
  int n = b >> 1, h = b & 1;
  float px = pos[2*n], py = pos[2*n + 1];
  int e0 = h * 3844;                      // 961*8/2
  for (int e = e0 + threadIdx.x; e < e0 + 3844; e += 256){
    int cg = e / 961, p = e - cg*961;
    int r = p / 31, c = p - r*31;
    float xsf = fminf(fmaxf(px + (float)(c - 15), 0.f), 1023.f);
    float ysf = fminf(fmaxf(py + (float)(r - 15), 0.f), 1023.f);
    int x0 = min((int)xsf, 1022);
    int y0 = min((int)ysf, 1022);
    float wx = xsf - (float)x0, wy = ysf - (float)y0;
    float w00 = (1.f-wy)*(1.f-wx), w01 = (1.f-wy)*wx;
    float w10 = wy*(1.f-wx),       w11 = wy*wx;
    size_t off = (size_t)y0*VHW + x0;
    const float* bp = vis + (size_t)(cg*8)*(VHW*VHW) + off;
    short8 v;
    #pragma unroll
    for (int i = 0; i < 8; ++i){
      const float* bb = bp + (size_t)i*(VHW*VHW);
      v[i] = (short)f2bf(bb[0]*w00 + bb[1]*w01 + bb[VHW]*w10 + bb[VHW+1]*w11);
    }
    *(short8*)&v_win[((size_t)cg*(1024*961) + (size_t)n*961 + p)*8] = v;
  }
}

// granule-major conv, dual B arrays (32 co per wave); NP = granule stride
template<int NP>
__device__ __forceinline__ void conv_tiles_g2(
    const unsigned short* __restrict__ in_t, const short8* B0, const short8* B1,
    int pb0, int pb1, int lk, f32x4& a00, f32x4& a01, f32x4& a10, f32x4& a11)
{
  const unsigned short* a0p = in_t + (lk*NP + pb0)*8;
  const unsigned short* a1p = in_t + (lk*NP + pb1)*8;
  #pragma unroll
  for (int ks = 0; ks < 18; ++ks){
    const int d = ks >> 1;
    const int dy = d / 3, dx = d - dy*3;
    const int off = (((ks & 1) ? 4*NP : 0) + dy*33 + dx) * 8;
    short8 A0 = *(const short8*)&a0p[off];
    short8 A1 = *(const short8*)&a1p[off];
    a00 = MFMA_B16(A0, B0[ks], a00);
    a01 = MFMA_B16(A0, B1[ks], a01);
    a10 = MFMA_B16(A1, B0[ks], a10);
    a11 = MFMA_B16(A1, B1[ks], a11);
  }
}

#define BANDR 6
#define NPA   330   // As positions & stride: 10 rows x 33 (330 % 8 == 2 -> conflict-free)
#define NPB_P 264   // Bs positions used: 8 rows x 33
#define NPB_S 266   // Bs granule stride (266 % 8 == 2 -> conflict-free)

__global__ __launch_bounds__(512, 2) void k_stconv(
    const unsigned short* __restrict__ v_win,
    const unsigned short* __restrict__ Wc1, const float* __restrict__ st1_b,
    const unsigned short* __restrict__ Wc2, const float* __restrict__ st2_b,
    const float* __restrict__ gst, float* __restrict__ st_vec)
{
  __shared__ __align__(16) unsigned short As[NPA*64];    // 42,240 B
  __shared__ __align__(16) unsigned short Bs[NPB_S*64];  // 34,048 B
  int n = blockIdx.x, band = blockIdx.y;
  int t = threadIdx.x;
  int w = t >> 6, l = t & 63, lr = l & 15, lk = l >> 4;
  int co0 = (w & 1) * 32;        // 2-way co split: two 16-co tiles per wave
  int mh = w >> 1;               // 4-way m split
  int ybaseV = band*BANDR - 2;
  int ybaseG = band*BANDR - 1;
  int rows_out = min(BANDR, 31 - band*BANDR);

  // stage As (granule-major, zero-pad halo); lanes consecutive p
  #pragma unroll
  for (int cg = 0; cg < 8; ++cg){
    for (int p = t; p < NPA; p += 512){
      int gr = p / 33, gc = p - gr*33;
      int yy = ybaseV + gr, xx = gc - 1;
      short8 v = {0,0,0,0,0,0,0,0};
      if (yy >= 0 && yy < 31 && xx >= 0 && xx < 31)
        v = *(const short8*)&v_win[((size_t)cg*(1024*961) + (size_t)n*961 + yy*31 + xx)*8];
      *(short8*)&As[(cg*NPA + p)*8] = v;
    }
  }
  // zero Bs (full stride extent)
  {
    short8 z = {0,0,0,0,0,0,0,0};
    for (int c = t; c < NPB_S*8; c += 512)
      *(short8*)&Bs[c*8] = z;
  }
  __syncthreads();

  // ---- phase 1: conv1 + gelu -> Bs (8 g1 rows x 31 cols; invalid rows stay 0)
  {
    short8 B0[18], B1[18];
    #pragma unroll
    for (int ks = 0; ks < 18; ++ks){
      B0[ks] = *(const short8*)&Wc1[(co0 + lr)*576 + ks*32 + lk*8];
      B1[ks] = *(const short8*)&Wc1[(co0 + 16 + lr)*576 + ks*32 + lk*8];
    }
    const int npos1 = 8*31;            // 248
    const int ntiles1 = 16;
    int mstart = mh * 4;
    int mend = min(mstart + 4, ntiles1);
    float bc0 = st1_b[co0 + lr], bc1 = st1_b[co0 + 16 + lr];
    int c0 = co0 + lr, c1 = co0 + 16 + lr;

    for (int mt = mstart; mt < mend; mt += 2){
      int s0 = min(mt*16 + lr, npos1 - 1);
      int s1 = min(mt*16 + 16 + lr, npos1 - 1);
      int ly0 = s0 / 31, x0p = s0 - ly0*31;
      int ly1 = s1 / 31, x1p = s1 - ly1*31;
      int pb0 = ly0*33 + x0p, pb1 = ly1*33 + x1p;
      f32x4 a00 = {0,0,0,0}, a01 = {0,0,0,0}, a10 = {0,0,0,0}, a11 = {0,0,0,0};
      conv_tiles_g2<NPA>(As, B0, B1, pb0, pb1, lk, a00, a01, a10, a11);
      #pragma unroll
      for (int i = 0; i < 4; ++i){
        int spo = mt*16 + lk*4 + i;
        if (spo < npos1){
          int ly = spo / 31, xx = spo - ly*31;
          int yy1 = ybaseG + ly;
          if (yy1 >= 0 && yy1 <= 30){
            int pB = ly*33 + xx + 1;
            Bs[((c0 >> 3)*NPB_S + pB)*8 + (c0 & 7)] = f2bf(gelu_f(a00[i] + bc0));
            Bs[((c1 >> 3)*NPB_S + pB)*8 + (c1 & 7)] = f2bf(gelu_f(a01[i] + bc1));
          }
        }
        int sp1 = spo + 16;
        if (sp1 < npos1 && mt + 1 < mend){
          int ly = sp1 / 31, xx = sp1 - ly*31;
          int yy1 = ybaseG + ly;
          if (yy1 >= 0 && yy1 <= 30){
            int pB = ly*33 + xx + 1;
            Bs[((c0 >> 3)*NPB_S + pB)*8 + (c0 & 7)] = f2bf(gelu_f(a10[i] + bc0));
            Bs[((c1 >> 3)*NPB_S + pB)*8 + (c1 & 7)] = f2bf(gelu_f(a11[i] + bc1));
          }
        }
      }
    }
  }
  __syncthreads();

  // ---- phase 2: conv2 + gelu + gaussian reduce -> st_vec
  {
    short8 B0[18], B1[18];
    #pragma unroll
    for (int ks = 0; ks < 18; ++ks){
      B0[ks] = *(const short8*)&Wc2[(co0 + lr)*576 + ks*32 + lk*8];
      B1[ks] = *(const short8*)&Wc2[(co0 + 16 + lr)*576 + ks*32 + lk*8];
    }
    int npos = rows_out * 31;
    int ntiles = (npos + 15) >> 4;
    int per = (ntiles + 3) >> 2;
    int mstart = mh * per;
    int mend = min(mstart + per, ntiles);
    float bc0 = st2_b[co0 + lr], bc1 = st2_b[co0 + 16 + lr];
    float vacc0 = 0.f, vacc1 = 0.f;

    for (int mt = mstart; mt < mend; mt += 2){
      int s0 = min(mt*16 + lr, npos - 1);
      int s1 = min(mt*16 + 16 + lr, npos - 1);
      int ly0 = s0 / 31, x0p = s0 - ly0*31;
      int ly1 = s1 / 31, x1p = s1 - ly1*31;
      int pb0 = ly0*33 + x0p, pb1 = ly1*33 + x1p;
      f32x4 a00 = {0,0,0,0}, a01 = {0,0,0,0}, a10 = {0,0,0,0}, a11 = {0,0,0,0};
      conv_tiles_g2<NPB_S>(Bs, B0, B1, pb0, pb1, lk, a00, a01, a10, a11);
      #pragma unroll
      for (int i = 0; i < 4; ++i){
        int spo = mt*16 + lk*4 + i;
        if (spo < npos){
          int ly = spo / 31, xx = spo - ly*31;
          float wt = gst[(band*BANDR + ly)*31 + xx];
          vacc0 += wt * gelu_f(a00[i] + bc0);
          vacc1 += wt * gelu_f(a01[i] + bc1);
        }
        int sp1 = spo + 16;
        if (sp1 < npos && mt + 1 < mend){
          int ly = sp1 / 31, xx = sp1 - ly*31;
          float wt = gst[(band*BANDR + ly)*31 + xx];
          vacc0 += wt * gelu_f(a10[i] + bc0);
          vacc1 += wt * gelu_f(a11[i] + bc1);
        }
      }
    }
    vacc0 += __shfl_xor(vacc0, 16); vacc0 += __shfl_xor(vacc0, 32);
    vacc1 += __shfl_xor(vacc1, 16); vacc1 += __shfl_xor(vacc1, 32);
    if (lk == 0){
      atomicAdd(&st_vec[n*64 + co0 + lr], vacc0);
      atomicAdd(&st_vec[n*64 + co0 + 16 + lr], vacc1);
    }
  }
}

// ---------------- bn path: fused gather + depthwise 7x7, 128-ch blocks ----------
__global__ __launch_bounds__(512, 4) void k_bnpre(
  const float* __restrict__ bott, const float* __restrict__ pos,
  const float* __restrict__ dw_w, const float* __restrict__ dw_b,
  unsigned short* __restrict__ x_bf, unsigned short* __restrict__ dcob)
{
  __shared__ float xt[128*123];
  __shared__ float wt4[121*4];
  __shared__ int   wo[121];
  int n = blockIdx.x, ch0 = blockIdx.y * 128;
  int t = threadIdx.x;
  float pbx = (pos[2*n]   + 0.5f)*0.25f - 0.5f;
  float pby = (pos[2*n+1] + 0.5f)*0.25f - 0.5f;

  if (t < 121){
    int r = t / 11, c = t - r*11;
    float xsf = fminf(fmaxf(pbx + (float)(c-5), 0.f), 255.f);
    float ysf = fminf(fmaxf(pby + (float)(r-5), 0.f), 255.f);
    int x0 = min((int)xsf, 254);
    int y0 = min((int)ysf, 254);
    float wx = xsf - (float)x0, wy = ysf - (float)y0;
    wo[t] = y0*FHW + x0;
    wt4[t*4+0] = (1.f-wy)*(1.f-wx);
    wt4[t*4+1] = (1.f-wy)*wx;
    wt4[t*4+2] = wy*(1.f-wx);
    wt4[t*4+3] = wy*wx;
  }
  __syncthreads();

  for (int e = t; e < 128*121; e += 512){
    int ch = e / 121, p = e - ch*121;
    const float* b = bott + (size_t)(ch0 + ch)*(FHW*FHW) + wo[p];
    float4 w = *(const float4*)&wt4[p*4];
    xt[ch*123 + p] = b[0]*w.x + b[1]*w.y + b[FHW]*w.z + b[FHW+1]*w.w;
  }
  __syncthreads();

  for (int e = t; e < 121*64; e += 512){
    int row = e >> 6, cp = (e & 63) << 1;
    float v0 = xt[cp*123 + row], v1 = xt[(cp+1)*123 + row];
    unsigned pk = (unsigned)f2bf(v0) | ((unsigned)f2bf(v1) << 16);
    *(unsigned*)&x_bf[(((size_t)n*121 + row) << 8) + ch0 + cp] = pk;
  }

  int ch = t & 127, part = t >> 7;
  float w[49];
  #pragma unroll
  for (int k = 0; k < 49; ++k) w[k] = dw_w[(ch0 + ch)*49 + k];
  float bias = dw_b[ch0 + ch];
  const float* xc = &xt[ch*123];
  for (int sp = part; sp < 121; sp += 4){
    int r = sp / 11, c = sp - r*11;
    float a = bias;
    #pragma unroll
    for (int dy = 0; dy < 7; ++dy){
      int ry = r + dy - 3;
      bool okr = (ry >= 0) && (ry < 11);
      #pragma unroll
      for (int dx = 0; dx < 7; ++dx){
        int cx = c + dx - 3;
        float xv = (okr && cx >= 0 && cx < 11) ? xc[ry*11 + cx] : 0.f;
        a = fmaf(xv, w[dy*7 + dx], a);
      }
    }
    dcob[(((size_t)n*121 + sp) << 8) + ch0 + ch] = f2bf(a);
  }
}

// ---------------- bn path: layernorm bf16 -> bf16 ----------------
__global__ __launch_bounds__(256) void k_ln(
  const unsigned short* __restrict__ dcob, const float* __restrict__ ln_g, const float* __restrict__ ln_b,
  unsigned short* __restrict__ normb)
{
  int m = blockIdx.x*4 + (threadIdx.x >> 6);
  int lane = threadIdx.x & 63;
  ushort4 raw = *(const ushort4*)&dcob[(size_t)m*256 + lane*4];
  float4 v = { bf2f(raw.x), bf2f(raw.y), bf2f(raw.z), bf2f(raw.w) };
  float s  = v.x+v.y+v.z+v.w;
  float ss = v.x*v.x + v.y*v.y + v.z*v.z + v.w*v.w;
  #pragma unroll
  for (int off = 32; off; off >>= 1){ s += __shfl_xor(s, off); ss += __shfl_xor(ss, off); }
  float mu  = s * 0.00390625f;
  float var = ss * 0.00390625f - mu*mu;
  float rstd = 1.0f / sqrtf(var + 1e-6f);
  float4 g = *(const float4*)&ln_g[lane*4];
  float4 b = *(const float4*)&ln_b[lane*4];
  ushort4 o;
  o.x = f2bf((v.x-mu)*rstd*g.x + b.x);
  o.y = f2bf((v.y-mu)*rstd*g.y + b.y);
  o.z = f2bf((v.z-mu)*rstd*g.z + b.z);
  o.w = f2bf((v.w-mu)*rstd*g.w + b.w);
  *(ushort4*)&normb[(size_t)m*256 + lane*4] = o;
}

// =======================================================================
// MLP as two m97-style GEMMs over M-chunks of 30976 rows.
// =======================================================================

__global__ __launch_bounds__(256, 3) void k_gemm1(
  const unsigned short* __restrict__ A, const unsigned short* __restrict__ B,
  const float* __restrict__ b1, unsigned short* __restrict__ H)
{
  __shared__ __align__(16) unsigned short sm[16384];
  unsigned short* As = sm;
  unsigned short* Bs = sm + 8192;
  int t = threadIdx.x, lane = t & 63, w = t >> 6;
  int lr = lane & 15, lk = lane >> 4;
  int p = blockIdx.x;
  int L = (p & 7) * 242 + (p >> 3);
  int m0 = (L >> 3) * 128, n0 = (L & 7) * 128;

  f32x4 acc[2][8];
  #pragma unroll
  for (int i = 0; i < 2; ++i)
    #pragma unroll
    for (int j = 0; j < 8; ++j) acc[i][j] = (f32x4){0,0,0,0};

  for (int ks = 0; ks < 4; ++ks){
    if (ks) __syncthreads();
    #pragma unroll
    for (int it = 0; it < 4; ++it){
      int j = t + it*256;
      int r = j >> 3, c = j & 7;
      int k8 = c ^ (r & 7);
      *(short8*)&As[j*8] = *(const short8*)&A[(size_t)(m0 + r)*256 + ks*64 + k8*8];
      *(short8*)&Bs[j*8] = *(const short8*)&B[(size_t)(n0 + r)*256 + ks*64 + k8*8];
    }
    __syncthreads();
    #pragma unroll
    for (int kk = 0; kk < 2; ++kk){
      int k8a = kk*4 + lk;
      short8 af[2];
      #pragma unroll
      for (int i = 0; i < 2; ++i){
        int ra = w*32 + i*16 + lr;
        af[i] = *(const short8*)&As[(ra*8 + (k8a ^ (ra & 7)))*8];
      }
      #pragma unroll
      for (int j = 0; j < 8; ++j){
        int rb = j*16 + lr;
        short8 bf = *(const short8*)&Bs[(rb*8 + (k8a ^ (rb & 7)))*8];
        acc[0][j] = MFMA_B16(af[0], bf, acc[0][j]);
        acc[1][j] = MFMA_B16(af[1], bf, acc[1][j]);
      }
    }
  }
  __syncthreads();
  #pragma unroll
  for (int i = 0; i < 2; ++i)
    #pragma unroll
    for (int j = 0; j < 8; ++j){
      int col = j*16 + lr;
      float bb = b1[n0 + col];
      #pragma unroll
      for (int q = 0; q < 4; ++q){
        int row = w*32 + i*16 + lk*4 + q;
        sm[row*128 + col] = f2bf(gelu_f(acc[i][j][q] + bb));
      }
    }
  __syncthreads();
  #pragma unroll
  for (int it = 0; it < 8; ++it){
    int e = t + it*256;
    int row = e >> 4, c8 = e & 15;
    *(short8*)&H[(size_t)(m0 + row)*1024 + n0 + c8*8] = *(const short8*)&sm[row*128 + c8*8];
  }
}

__global__ __launch_bounds__(256, 4) void k_gemm2(
  const unsigned short* __restrict__ A, const unsigned short* __restrict__ B,
  const float* __restrict__ b2v, const float* __restrict__ lsg,
  const unsigned short* __restrict__ xres, unsigned short* __restrict__ Y)
{
  __shared__ __align__(16) unsigned short sm[16384];
  unsigned short* As = sm;
  unsigned short* Bs = sm + 8192;
  int t = threadIdx.x, lane = t & 63, w = t >> 6;
  int lr = lane & 15, lk = lane >> 4;
  int p = blockIdx.x;
  int L = (p & 7) * 121 + (p >> 3);
  int m0 = (L >> 2) * 128, n0 = (L & 3) * 64;

  f32x4 acc[2][4];
  #pragma unroll
  for (int i = 0; i < 2; ++i)
    #pragma unroll
    for (int j = 0; j < 4; ++j) acc[i][j] = (f32x4){0,0,0,0};

  for (int ks = 0; ks < 16; ++ks){
    if (ks) __syncthreads();
    #pragma unroll
    for (int it = 0; it < 4; ++it){
      int j = t + it*256;
      int r = j >> 3, c = j & 7;
      int k8 = c ^ (r & 7);
      *(short8*)&As[j*8] = *(const short8*)&A[(size_t)(m0 + r)*1024 + ks*64 + k8*8];
    }
    #pragma unroll
    for (int it = 0; it < 2; ++it){
      int j = t + it*256;
      int r = j >> 3, c = j & 7;
      int k8 = c ^ (r & 7);
      *(short8*)&Bs[j*8] = *(const short8*)&B[(size_t)(n0 + r)*1024 + ks*64 + k8*8];
    }
    __syncthreads();
    #pragma unroll
    for (int kk = 0; kk < 2; ++kk){
      int k8a = kk*4 + lk;
      short8 af[2];
      #pragma unroll
      for (int i = 0; i < 2; ++i){
        int ra = w*32 + i*16 + lr;
        af[i] = *(const short8*)&As[(ra*8 + (k8a ^ (ra & 7)))*8];
      }
      #pragma unroll
      for (int j = 0; j < 4; ++j){
        int rb = j*16 + lr;
        short8 bf = *(const short8*)&Bs[(rb*8 + (k8a ^ (rb & 7)))*8];
        acc[0][j] = MFMA_B16(af[0], bf, acc[0][j]);
        acc[1][j] = MFMA_B16(af[1], bf, acc[1][j]);
      }
    }
  }
  __syncthreads();
  float* Cs = (float*)sm;
  #pragma unroll
  for (int i = 0; i < 2; ++i)
    #pragma unroll
    for (int j = 0; j < 4; ++j){
      int col = j*16 + lr;
      #pragma unroll
      for (int q = 0; q < 4; ++q){
        int row = w*32 + i*16 + lk*4 + q;
        Cs[row*64 + col] = acc[i][j][q];
      }
    }
  __syncthreads();
  #pragma unroll
  for (int it = 0; it < 8; ++it){
    int e4 = t + it*256;
    int row = e4 >> 4, c4 = (e4 & 15) * 4;
    float4 cv = *(const float4*)&Cs[row*64 + c4];
    size_t grow = (size_t)(m0 + row);
    ushort4 xr = *(const ushort4*)&xres[grow*256 + n0 + c4];
    float4 bb = *(const float4*)&b2v[n0 + c4];
    float4 gm = *(const float4*)&lsg[n0 + c4];
    ushort4 o;
    o.x = f2bf(fmaf(cv.x + bb.x, gm.x, bf2f(xr.x)));
    o.y = f2bf(fmaf(cv.y + bb.y, gm.y, bf2f(xr.y)));
    o.z = f2bf(fmaf(cv.z + bb.z, gm.z, bf2f(xr.z)));
    o.w = f2bf(fmaf(cv.w + bb.w, gm.w, bf2f(xr.w)));
    *(ushort4*)&Y[grow*256 + n0 + c4] = o;
  }
}

// ---------------- bn path: 1x1 conv 256->128 (MFMA) + gelu + gaussian reduce ----------
__global__ __launch_bounds__(256) void k_bnvec(
  const unsigned short* __restrict__ yb, const unsigned short* __restrict__ bnWb,
  const float* __restrict__ bn_b, const float* __restrict__ gbn, float* __restrict__ bn_vec)
{
  int n = blockIdx.x, t = threadIdx.x;
  int w = t >> 6, l = t & 63, lr = l & 15, lk = l >> 4;
  f32x4 acc[8][2];
  #pragma unroll
  for (int mt = 0; mt < 8; ++mt){ acc[mt][0] = (f32x4){0,0,0,0}; acc[mt][1] = (f32x4){0,0,0,0}; }

  #pragma unroll
  for (int ks = 0; ks < 8; ++ks){
    short8 b0 = *(const short8*)&bnWb[(size_t)(w*32 + lr)*256 + ks*32 + lk*8];
    short8 b1 = *(const short8*)&bnWb[(size_t)(w*32 + 16 + lr)*256 + ks*32 + lk*8];
    #pragma unroll
    for (int mt = 0; mt < 8; ++mt){
      int row = min(mt*16 + lr, 120);
      short8 a = *(const short8*)&yb[((size_t)n*121 + row)*256 + ks*32 + lk*8];
      acc[mt][0] = MFMA_B16(a, b0, acc[mt][0]);
      acc[mt][1] = MFMA_B16(a, b1, acc[mt][1]);
    }
  }

  float s0 = 0.f, s1 = 0.f;
  float bb0 = bn_b[w*32 + lr], bb1 = bn_b[w*32 + 16 + lr];
  #pragma unroll
  for (int mt = 0; mt < 8; ++mt)
    #pragma unroll
    for (int i = 0; i < 4; ++i){
      int row = mt*16 + lk*4 + i;
      if (row < 121){
        float g = gbn[row];
        s0 += g * gelu_f(acc[mt][0][i] + bb0);
        s1 += g * gelu_f(acc[mt][1][i] + bb1);
      }
    }
  s0 += __shfl_xor(s0, 16); s0 += __shfl_xor(s0, 32);
  s1 += __shfl_xor(s1, 16); s1 += __shfl_xor(s1, 32);
  if (lk == 0){
    bn_vec[n*128 + w*32 + lr] = s0;
    bn_vec[n*128 + w*32 + 16 + lr] = s1;
  }
}

// ---------------- head: 4 n per block ----------------
__global__ __launch_bounds__(256) void k_head(
  const float* __restrict__ bn_vec, const float* __restrict__ st_vec,
  const float* __restrict__ tr1_w, const float* __restrict__ tr1_b,
  const float* __restrict__ tr2_w, const float* __restrict__ tr2_b,
  const float* __restrict__ md_w, const float* __restrict__ md_b,
  const float* __restrict__ init_m,
  float* __restrict__ out)
{
  __shared__ float feat4[4*192];
  __shared__ float h14[4*256];
  __shared__ float h24[4*256];
  __shared__ float dlt4[4*961];
  __shared__ float yv4[4*961];
  int t = threadIdx.x;
  int n0 = blockIdx.x * 4;
  float* morph_out = out;
  float* delta_out = out + 984064;
  float* feat_out  = out + 1968128;

  for (int e = t; e < 4*192; e += 256){
    int ni = e / 192, j = e - ni*192;
    float v = (j < 128) ? bn_vec[(n0+ni)*128 + j] : st_vec[(n0+ni)*64 + j - 128];
    feat4[e] = v;
    feat_out[(size_t)(n0+ni)*192 + j] = v;
  }
  __syncthreads();
  {
    float a0 = tr1_b[t], a1 = a0, a2 = a0, a3 = a0;
    const float* wr = &tr1_w[t*192];
    for (int k = 0; k < 192; ++k){
      float wk = wr[k];
      a0 = fmaf(feat4[k],       wk, a0);
      a1 = fmaf(feat4[192 + k], wk, a1);
      a2 = fmaf(feat4[384 + k], wk, a2);
      a3 = fmaf(feat4[576 + k], wk, a3);
    }
    h14[t] = gelu_f(a0); h14[256 + t] = gelu_f(a1);
    h14[512 + t] = gelu_f(a2); h14[768 + t] = gelu_f(a3);
  }
  __syncthreads();
  {
    float a0 = tr2_b[t], a1 = a0, a2 = a0, a3 = a0;
    const float* wr = &tr2_w[t*256];
    for (int k = 0; k < 256; ++k){
      float wk = wr[k];
      a0 = fmaf(h14[k],       wk, a0);
      a1 = fmaf(h14[256 + k], wk, a1);
      a2 = fmaf(h14[512 + k], wk, a2);
      a3 = fmaf(h14[768 + k], wk, a3);
    }
    h24[t] = gelu_f(a0); h24[256 + t] = gelu_f(a1);
    h24[512 + t] = gelu_f(a2); h24[768 + t] = gelu_f(a3);
  }
  __syncthreads();
  for (int j = t; j < 961; j += 256){
    float b = md_b[j];
    float a0 = b, a1 = b, a2 = b, a3 = b;
    const float* wr = &md_w[(size_t)j*256];
    for (int k = 0; k < 256; ++k){
      float wk = wr[k];
      a0 = fmaf(h24[k],       wk, a0);
      a1 = fmaf(h24[256 + k], wk, a1);
      a2 = fmaf(h24[512 + k], wk, a2);
      a3 = fmaf(h24[768 + k], wk, a3);
    }
    float d0 = tanhf(a0), d1 = tanhf(a1), d2 = tanhf(a2), d3 = tanhf(a3);
    dlt4[j] = d0; dlt4[961 + j] = d1; dlt4[1922 + j] = d2; dlt4[2883 + j] = d3;
    delta_out[(size_t)(n0+0)*961 + j] = d0;
    delta_out[(size_t)(n0+1)*961 + j] = d1;
    delta_out[(size_t)(n0+2)*961 + j] = d2;
    delta_out[(size_t)(n0+3)*961 + j] = d3;
  }
  __syncthreads();

  int g = t >> 6, l64 = t & 63;
  int n = n0 + g;
  const float* im = &init_m[(size_t)n*961];
  float loc = 0.f;
  for (int j = l64; j < 961; j += 64) loc += fmaxf(im[j], 0.f);
  #pragma unroll
  for (int off = 32; off; off >>= 1) loc += __shfl_xor(loc, off);
  float s0 = loc + 1e-8f;
  float loc2 = 0.f;
  for (int j = l64; j < 961; j += 64){
    float imn = fmaxf(im[j], 0.f) / s0;
    float x = fmaxf(imn, 1e-8f);
    float base = x + logf(-expm1f(-x));
    float z = base + 1.5f * dlt4[g*961 + j];
    float y = fmaxf(z, 0.f) + log1pf(expf(-fabsf(z)));
    yv4[g*961 + j] = y;
    loc2 += y;
  }
  #pragma unroll
  for (int off = 32; off; off >>= 1) loc2 += __shfl_xor(loc2, off);
  float s1 = loc2 + 1e-8f;
  for (int j = l64; j < 961; j += 64)
    morph_out[(size_t)n*961 + j] = yv4[g*961 + j] / s1;
}

// ---------------- launch ----------------
extern "C" void kernel_launch(void* const* d_in, const int* in_sizes, int n_in,
                              void* d_out, int out_size, void* d_ws, size_t ws_size,
                              hipStream_t stream)
{
  const float* bott = (const float*)d_in[0];
  const float* vis  = (const float*)d_in[1];
  const float* pos  = (const float*)d_in[2];
  const float* initm= (const float*)d_in[3];
  const float* dw_w = (const float*)d_in[4];
  const float* dw_b = (const float*)d_in[5];
  const float* ln_g = (const float*)d_in[6];
  const float* ln_b = (const float*)d_in[7];
  const float* pw1_w= (const float*)d_in[8];
  const float* pw1_b= (const float*)d_in[9];
  const float* pw2_w= (const float*)d_in[10];
  const float* pw2_b= (const float*)d_in[11];
  const float* lsg  = (const float*)d_in[12];
  const float* bn_w = (const float*)d_in[13];
  const float* bn_b = (const float*)d_in[14];
  const float* st1_w= (const float*)d_in[15];
  const float* st1_b= (const float*)d_in[16];
  const float* st2_w= (const float*)d_in[17];
  const float* st2_b= (const float*)d_in[18];
  const float* tr1_w= (const float*)d_in[19];
  const float* tr1_b= (const float*)d_in[20];
  const float* tr2_w= (const float*)d_in[21];
  const float* tr2_b= (const float*)d_in[22];
  const float* md_w = (const float*)d_in[23];
  const float* md_b = (const float*)d_in[24];

  char* ws = (char*)d_ws;
  // Region A (126.9MB): v_win (st path) -> dcob (bnpre) -> Hq|yb (gemms)
  unsigned short* v_win = (unsigned short*)(ws);
  unsigned short* dcob  = (unsigned short*)(ws);
  unsigned short* Hq    = (unsigned short*)(ws);
  unsigned short* yb    = (unsigned short*)(ws + 63438848);
  // Regions B+C (126.9MB): x_bf | normb
  unsigned short* x_bf  = (unsigned short*)(ws + 126877696);
  unsigned short* normb = (unsigned short*)(ws + 190316544);
  char* S = ws + 253755392;
  float* st_vec = (float*)(S);
  float* bn_vec = (float*)(S + 262144);
  float* gbn    = (float*)(S + 786432);
  float* gst    = (float*)(S + 786944);
  unsigned short* W1b  = (unsigned short*)(S + 791040);
  unsigned short* W2b  = (unsigned short*)(S + 1315328);
  unsigned short* Wc1  = (unsigned short*)(S + 1839616);
  unsigned short* Wc2  = (unsigned short*)(S + 1913344);
  unsigned short* bnWb = (unsigned short*)(S + 1987072);

  hipMemsetAsync(st_vec, 0, 1024*64*sizeof(float), stream);
  k_gauss<<<1, 256, 0, stream>>>(gbn, gst);
  k_trans<<<256, 256, 0, stream>>>(pw1_w, pw2_w, bn_w, st1_w, st2_w, W1b, W2b, bnWb, Wc1, Wc2);

  // st path: gather (A = v_win), fused conv1+conv2 (band=6, 2 blk/CU) -> st_vec
  k_stg<<<2048, 256, 0, stream>>>(vis, pos, v_win);
  k_stconv<<<dim3(1024, 6), 512, 0, stream>>>(v_win, Wc1, st1_b, Wc2, st2_b, gst, st_vec);

  // bn pre (v_win dead: dcob -> A); 128-ch blocks
  k_bnpre<<<dim3(1024, 2), 512, 0, stream>>>(bott, pos, dw_w, dw_b, x_bf, dcob);
  k_ln<<<30976, 256, 0, stream>>>(dcob, ln_g, ln_b, normb);

  // MLP: 4 M-chunks of two GEMMs (dcob dead; A = Hq | yb)
  for (int q = 0; q < 4; ++q){
    size_t ro = (size_t)q * MQ;
    k_gemm1<<<1936, 256, 0, stream>>>(normb + ro*256, W1b, pw1_b, Hq);
    k_gemm2<<<968, 256, 0, stream>>>(Hq, W2b, pw2_b, lsg, x_bf + ro*256, yb + ro*256);
  }
  k_bnvec<<<1024, 256, 0, stream>>>(yb, bnWb, bn_b, gbn, bn_vec);

  // head
  k_head<<<256, 256, 0, stream>>>(bn_vec, st_vec, tr1_w, tr1_b, tr2_w, tr2_b,
                                  md_w, md_b, initm, (float*)d_out);
}

// Round 15
// 1256.294 us; speedup vs baseline: 1.2031x; 1.2031x over previous
//
#include <hip/hip_runtime.h>
#include <math.h>

// ---------------- constants ----------------
#define N_SRC 1024
#define VHW 1024
#define FHW 256
#define MQ 30976            // M-chunk rows (123904/4), = 242 * 128

typedef __attribute__((ext_vector_type(8))) short short8;
typedef __attribute__((ext_vector_type(4))) float f32x4;

#define MFMA_B16(a,b,c) __builtin_amdgcn_mfma_f32_16x16x32_bf16((a),(b),(c),0,0,0)

__device__ __forceinline__ float gelu_f(float x){
  return 0.5f * x * (1.0f + erff(x * 0.70710678118654752440f));
}
__device__ __forceinline__ unsigned short f2bf(float f){
  union { float f; unsigned u; } x; x.f = f;
  unsigned r = x.u + 0x7fffu + ((x.u >> 16) & 1u);
  return (unsigned short)(r >> 16);
}
__device__ __forceinline__ float bf2f(unsigned short h){
  union { unsigned u; float f; } x; x.u = ((unsigned)h) << 16;
  return x.f;
}

// ---------------- gaussian tables ----------------
__global__ void k_gauss(float* __restrict__ gbn, float* __restrict__ gst){
  __shared__ double red[256];
  int t = threadIdx.x;
  {
    double v = 0.0;
    if (t < 121){
      int r = t / 11, c = t % 11;
      double y = -1.0 + 2.0 * (double)r / 10.0;
      double x = -1.0 + 2.0 * (double)c / 10.0;
      v = exp(-(x*x + y*y) / (2.0 * 0.4 * 0.4));
    }
    red[t] = v; __syncthreads();
    for (int s = 128; s > 0; s >>= 1){ if (t < s) red[t] += red[t+s]; __syncthreads(); }
    double sum = red[0];
    __syncthreads();
    if (t < 121) gbn[t] = (float)(v / sum);
    __syncthreads();
  }
  {
    double vals[4]; double loc = 0.0;
    #pragma unroll
    for (int i = 0; i < 4; ++i){
      int j = t + 256*i;
      double v = 0.0;
      if (j < 961){
        int r = j / 31, c = j % 31;
        double y = -1.0 + 2.0 * (double)r / 30.0;
        double x = -1.0 + 2.0 * (double)c / 30.0;
        v = exp(-(x*x + y*y) / (2.0 * 0.4 * 0.4));
      }
      vals[i] = v; loc += v;
    }
    red[t] = loc; __syncthreads();
    for (int s = 128; s > 0; s >>= 1){ if (t < s) red[t] += red[t+s]; __syncthreads(); }
    double sum = red[0];
    __syncthreads();
    #pragma unroll
    for (int i = 0; i < 4; ++i){
      int j = t + 256*i;
      if (j < 961) gst[j] = (float)(vals[i] / sum);
    }
  }
}

// ---------------- weight conversion ----------------
__global__ void k_trans(const float* __restrict__ pw1_w, const float* __restrict__ pw2_w,
                        const float* __restrict__ bn_w,
                        const float* __restrict__ st1_w, const float* __restrict__ st2_w,
                        unsigned short* __restrict__ W1b, unsigned short* __restrict__ W2b,
                        unsigned short* __restrict__ bnWb,
                        unsigned short* __restrict__ Wc1, unsigned short* __restrict__ Wc2){
  int stride = gridDim.x * blockDim.x;
  int i0 = blockIdx.x * blockDim.x + threadIdx.x;
  for (int e = i0; e < 256*1024; e += stride) W1b[e] = f2bf(pw1_w[e]);
  for (int e = i0; e < 256*1024; e += stride) W2b[e] = f2bf(pw2_w[e]);
  for (int e = i0; e < 128*256; e += stride) bnWb[e] = f2bf(bn_w[e]);
  for (int e = i0; e < 64*576; e += stride){
    int co = e / 576, r = e % 576, d = r >> 6, ci = r & 63;
    Wc1[e] = f2bf(st1_w[(co*64 + ci)*9 + d]);
    Wc2[e] = f2bf(st2_w[(co*64 + ci)*9 + d]);
  }
}

// =======================================================================
// st path:
//   k_stg    : wave-coalesced gather vis -> v_win bf16 plane-major [8cg][n*961][8]
//   k_stconv : fused conv1+conv2, granule-major LDS; strides 330/266 (== 2 mod 8
//              -> lk bank phases 0/8/16/24, conflict-free); 4-way co, 2 blk/CU
// =======================================================================

__global__ __launch_bounds__(256) void k_stg(
    const float* __restrict__ vis, const float* __restrict__ pos,
    unsigned short* __restrict__ v_win)
{
  int b = blockIdx.x;
  int n = b >> 1, h = b & 1;
  float px = pos[2*n], py = pos[2*n + 1];
  int e0 = h * 3844;                      // 961*8/2
  for (int e = e0 + threadIdx.x; e < e0 + 3844; e += 256){
    int cg = e / 961, p = e - cg*961;
    int r = p / 31, c = p - r*31;
    float xsf = fminf(fmaxf(px + (float)(c - 15), 0.f), 1023.f);
    float ysf = fminf(fmaxf(py + (float)(r - 15), 0.f), 1023.f);
    int x0 = min((int)xsf, 1022);
    int y0 = min((int)ysf, 1022);
    float wx = xsf - (float)x0, wy = ysf - (float)y0;
    float w00 = (1.f-wy)*(1.f-wx), w01 = (1.f-wy)*wx;
    float w10 = wy*(1.f-wx),       w11 = wy*wx;
    size_t off = (size_t)y0*VHW + x0;
    const float* bp = vis + (size_t)(cg*8)*(VHW*VHW) + off;
    short8 v;
    #pragma unroll
    for (int i = 0; i < 8; ++i){
      const float* bb = bp + (size_t)i*(VHW*VHW);
      v[i] = (short)f2bf(bb[0]*w00 + bb[1]*w01 + bb[VHW]*w10 + bb[VHW+1]*w11);
    }
    *(short8*)&v_win[((size_t)cg*(1024*961) + (size_t)n*961 + p)*8] = v;
  }
}

// granule-major conv, single B array (16 co per wave); NP = granule stride
template<int NP>
__device__ __forceinline__ void conv_tiles_g1(
    const unsigned short* __restrict__ in_t, const short8* B0,
    int pb0, int pb1, int lk, f32x4& a00, f32x4& a10)
{
  const unsigned short* a0p = in_t + (lk*NP + pb0)*8;
  const unsigned short* a1p = in_t + (lk*NP + pb1)*8;
  #pragma unroll
  for (int ks = 0; ks < 18; ++ks){
    const int d = ks >> 1;
    const int dy = d / 3, dx = d - dy*3;
    const int off = (((ks & 1) ? 4*NP : 0) + dy*33 + dx) * 8;
    short8 A0 = *(const short8*)&a0p[off];
    short8 A1 = *(const short8*)&a1p[off];
    a00 = MFMA_B16(A0, B0[ks], a00);
    a10 = MFMA_B16(A1, B0[ks], a10);
  }
}

#define BANDR 6
#define NPA   330   // As positions & stride: 10 rows x 33 (330 % 8 == 2)
#define NPB_P 264   // Bs positions used: 8 rows x 33
#define NPB_S 266   // Bs granule stride   (266 % 8 == 2)

__global__ __launch_bounds__(512, 4) void k_stconv(
    const unsigned short* __restrict__ v_win,
    const unsigned short* __restrict__ Wc1, const float* __restrict__ st1_b,
    const unsigned short* __restrict__ Wc2, const float* __restrict__ st2_b,
    const float* __restrict__ gst, float* __restrict__ st_vec)
{
  __shared__ __align__(16) unsigned short As[NPA*64];    // 42,240 B
  __shared__ __align__(16) unsigned short Bs[NPB_S*64];  // 34,048 B
  int n = blockIdx.x, band = blockIdx.y;
  int t = threadIdx.x;
  int w = t >> 6, l = t & 63, lr = l & 15, lk = l >> 4;
  int co0 = (w & 3) * 16;        // 4-way co split: one 16-co tile per wave
  int mh = w >> 2;               // 2-way m split
  int ybaseV = band*BANDR - 2;
  int ybaseG = band*BANDR - 1;
  int rows_out = min(BANDR, 31 - band*BANDR);

  // stage As (granule-major, zero-pad halo); lanes consecutive p
  #pragma unroll
  for (int cg = 0; cg < 8; ++cg){
    for (int p = t; p < NPA; p += 512){
      int gr = p / 33, gc = p - gr*33;
      int yy = ybaseV + gr, xx = gc - 1;
      short8 v = {0,0,0,0,0,0,0,0};
      if (yy >= 0 && yy < 31 && xx >= 0 && xx < 31)
        v = *(const short8*)&v_win[((size_t)cg*(1024*961) + (size_t)n*961 + yy*31 + xx)*8];
      *(short8*)&As[(cg*NPA + p)*8] = v;
    }
  }
  // zero Bs (full padded extent)
  {
    short8 z = {0,0,0,0,0,0,0,0};
    for (int c = t; c < NPB_S*8; c += 512)
      *(short8*)&Bs[c*8] = z;
  }
  __syncthreads();

  // ---- phase 1: conv1 + gelu -> Bs (8 g1 rows x 31 cols; invalid rows stay 0)
  {
    short8 B0[18];
    #pragma unroll
    for (int ks = 0; ks < 18; ++ks)
      B0[ks] = *(const short8*)&Wc1[(co0 + lr)*576 + ks*32 + lk*8];
    const int npos1 = 8*31;            // 248
    const int ntiles1 = 16;
    int mstart = mh * 8;
    int mend = min(mstart + 8, ntiles1);
    float bc0 = st1_b[co0 + lr];
    int c0 = co0 + lr;

    for (int mt = mstart; mt < mend; mt += 2){
      int s0 = min(mt*16 + lr, npos1 - 1);
      int s1 = min(mt*16 + 16 + lr, npos1 - 1);
      int ly0 = s0 / 31, x0p = s0 - ly0*31;
      int ly1 = s1 / 31, x1p = s1 - ly1*31;
      int pb0 = ly0*33 + x0p, pb1 = ly1*33 + x1p;
      f32x4 a00 = {0,0,0,0}, a10 = {0,0,0,0};
      conv_tiles_g1<NPA>(As, B0, pb0, pb1, lk, a00, a10);
      #pragma unroll
      for (int i = 0; i < 4; ++i){
        int spo = mt*16 + lk*4 + i;
        if (spo < npos1){
          int ly = spo / 31, xx = spo - ly*31;
          int yy1 = ybaseG + ly;
          if (yy1 >= 0 && yy1 <= 30){
            int pB = ly*33 + xx + 1;
            Bs[((c0 >> 3)*NPB_S + pB)*8 + (c0 & 7)] = f2bf(gelu_f(a00[i] + bc0));
          }
        }
        int sp1 = spo + 16;
        if (sp1 < npos1 && mt + 1 < mend){
          int ly = sp1 / 31, xx = sp1 - ly*31;
          int yy1 = ybaseG + ly;
          if (yy1 >= 0 && yy1 <= 30){
            int pB = ly*33 + xx + 1;
            Bs[((c0 >> 3)*NPB_S + pB)*8 + (c0 & 7)] = f2bf(gelu_f(a10[i] + bc0));
          }
        }
      }
    }
  }
  __syncthreads();

  // ---- phase 2: conv2 + gelu + gaussian reduce -> st_vec
  {
    short8 B0[18];
    #pragma unroll
    for (int ks = 0; ks < 18; ++ks)
      B0[ks] = *(const short8*)&Wc2[(co0 + lr)*576 + ks*32 + lk*8];
    int npos = rows_out * 31;
    int ntiles = (npos + 15) >> 4;
    int per = (ntiles + 1) >> 1;
    int mstart = mh * per;
    int mend = min(mstart + per, ntiles);
    float bc0 = st2_b[co0 + lr];
    float vacc0 = 0.f;

    for (int mt = mstart; mt < mend; mt += 2){
      int s0 = min(mt*16 + lr, npos - 1);
      int s1 = min(mt*16 + 16 + lr, npos - 1);
      int ly0 = s0 / 31, x0p = s0 - ly0*31;
      int ly1 = s1 / 31, x1p = s1 - ly1*31;
      int pb0 = ly0*33 + x0p, pb1 = ly1*33 + x1p;
      f32x4 a00 = {0,0,0,0}, a10 = {0,0,0,0};
      conv_tiles_g1<NPB_S>(Bs, B0, pb0, pb1, lk, a00, a10);
      #pragma unroll
      for (int i = 0; i < 4; ++i){
        int spo = mt*16 + lk*4 + i;
        if (spo < npos){
          int ly = spo / 31, xx = spo - ly*31;
          float wt = gst[(band*BANDR + ly)*31 + xx];
          vacc0 += wt * gelu_f(a00[i] + bc0);
        }
        int sp1 = spo + 16;
        if (sp1 < npos && mt + 1 < mend){
          int ly = sp1 / 31, xx = sp1 - ly*31;
          float wt = gst[(band*BANDR + ly)*31 + xx];
          vacc0 += wt * gelu_f(a10[i] + bc0);
        }
      }
    }
    vacc0 += __shfl_xor(vacc0, 16); vacc0 += __shfl_xor(vacc0, 32);
    if (lk == 0)
      atomicAdd(&st_vec[n*64 + co0 + lr], vacc0);
  }
}

// ---------------- bn path: fused gather + depthwise 7x7, 128-ch blocks ----------
__global__ __launch_bounds__(512, 4) void k_bnpre(
  const float* __restrict__ bott, const float* __restrict__ pos,
  const float* __restrict__ dw_w, const float* __restrict__ dw_b,
  unsigned short* __restrict__ x_bf, unsigned short* __restrict__ dcob)
{
  __shared__ float xt[128*123];
  __shared__ float wt4[121*4];
  __shared__ int   wo[121];
  int n = blockIdx.x, ch0 = blockIdx.y * 128;
  int t = threadIdx.x;
  float pbx = (pos[2*n]   + 0.5f)*0.25f - 0.5f;
  float pby = (pos[2*n+1] + 0.5f)*0.25f - 0.5f;

  if (t < 121){
    int r = t / 11, c = t - r*11;
    float xsf = fminf(fmaxf(pbx + (float)(c-5), 0.f), 255.f);
    float ysf = fminf(fmaxf(pby + (float)(r-5), 0.f), 255.f);
    int x0 = min((int)xsf, 254);
    int y0 = min((int)ysf, 254);
    float wx = xsf - (float)x0, wy = ysf - (float)y0;
    wo[t] = y0*FHW + x0;
    wt4[t*4+0] = (1.f-wy)*(1.f-wx);
    wt4[t*4+1] = (1.f-wy)*wx;
    wt4[t*4+2] = wy*(1.f-wx);
    wt4[t*4+3] = wy*wx;
  }
  __syncthreads();

  for (int e = t; e < 128*121; e += 512){
    int ch = e / 121, p = e - ch*121;
    const float* b = bott + (size_t)(ch0 + ch)*(FHW*FHW) + wo[p];
    float4 w = *(const float4*)&wt4[p*4];
    xt[ch*123 + p] = b[0]*w.x + b[1]*w.y + b[FHW]*w.z + b[FHW+1]*w.w;
  }
  __syncthreads();

  for (int e = t; e < 121*64; e += 512){
    int row = e >> 6, cp = (e & 63) << 1;
    float v0 = xt[cp*123 + row], v1 = xt[(cp+1)*123 + row];
    unsigned pk = (unsigned)f2bf(v0) | ((unsigned)f2bf(v1) << 16);
    *(unsigned*)&x_bf[(((size_t)n*121 + row) << 8) + ch0 + cp] = pk;
  }

  int ch = t & 127, part = t >> 7;
  float w[49];
  #pragma unroll
  for (int k = 0; k < 49; ++k) w[k] = dw_w[(ch0 + ch)*49 + k];
  float bias = dw_b[ch0 + ch];
  const float* xc = &xt[ch*123];
  for (int sp = part; sp < 121; sp += 4){
    int r = sp / 11, c = sp - r*11;
    float a = bias;
    #pragma unroll
    for (int dy = 0; dy < 7; ++dy){
      int ry = r + dy - 3;
      bool okr = (ry >= 0) && (ry < 11);
      #pragma unroll
      for (int dx = 0; dx < 7; ++dx){
        int cx = c + dx - 3;
        float xv = (okr && cx >= 0 && cx < 11) ? xc[ry*11 + cx] : 0.f;
        a = fmaf(xv, w[dy*7 + dx], a);
      }
    }
    dcob[(((size_t)n*121 + sp) << 8) + ch0 + ch] = f2bf(a);
  }
}

// ---------------- bn path: layernorm bf16 -> bf16 ----------------
__global__ __launch_bounds__(256) void k_ln(
  const unsigned short* __restrict__ dcob, const float* __restrict__ ln_g, const float* __restrict__ ln_b,
  unsigned short* __restrict__ normb)
{
  int m = blockIdx.x*4 + (threadIdx.x >> 6);
  int lane = threadIdx.x & 63;
  ushort4 raw = *(const ushort4*)&dcob[(size_t)m*256 + lane*4];
  float4 v = { bf2f(raw.x), bf2f(raw.y), bf2f(raw.z), bf2f(raw.w) };
  float s  = v.x+v.y+v.z+v.w;
  float ss = v.x*v.x + v.y*v.y + v.z*v.z + v.w*v.w;
  #pragma unroll
  for (int off = 32; off; off >>= 1){ s += __shfl_xor(s, off); ss += __shfl_xor(ss, off); }
  float mu  = s * 0.00390625f;
  float var = ss * 0.00390625f - mu*mu;
  float rstd = 1.0f / sqrtf(var + 1e-6f);
  float4 g = *(const float4*)&ln_g[lane*4];
  float4 b = *(const float4*)&ln_b[lane*4];
  ushort4 o;
  o.x = f2bf((v.x-mu)*rstd*g.x + b.x);
  o.y = f2bf((v.y-mu)*rstd*g.y + b.y);
  o.z = f2bf((v.z-mu)*rstd*g.z + b.z);
  o.w = f2bf((v.w-mu)*rstd*g.w + b.w);
  *(ushort4*)&normb[(size_t)m*256 + lane*4] = o;
}

// =======================================================================
// MLP as two m97-style GEMMs over M-chunks of 30976 rows.
// =======================================================================

__global__ __launch_bounds__(256, 3) void k_gemm1(
  const unsigned short* __restrict__ A, const unsigned short* __restrict__ B,
  const float* __restrict__ b1, unsigned short* __restrict__ H)
{
  __shared__ __align__(16) unsigned short sm[16384];
  unsigned short* As = sm;
  unsigned short* Bs = sm + 8192;
  int t = threadIdx.x, lane = t & 63, w = t >> 6;
  int lr = lane & 15, lk = lane >> 4;
  int p = blockIdx.x;
  int L = (p & 7) * 242 + (p >> 3);
  int m0 = (L >> 3) * 128, n0 = (L & 7) * 128;

  f32x4 acc[2][8];
  #pragma unroll
  for (int i = 0; i < 2; ++i)
    #pragma unroll
    for (int j = 0; j < 8; ++j) acc[i][j] = (f32x4){0,0,0,0};

  for (int ks = 0; ks < 4; ++ks){
    if (ks) __syncthreads();
    #pragma unroll
    for (int it = 0; it < 4; ++it){
      int j = t + it*256;
      int r = j >> 3, c = j & 7;
      int k8 = c ^ (r & 7);
      *(short8*)&As[j*8] = *(const short8*)&A[(size_t)(m0 + r)*256 + ks*64 + k8*8];
      *(short8*)&Bs[j*8] = *(const short8*)&B[(size_t)(n0 + r)*256 + ks*64 + k8*8];
    }
    __syncthreads();
    #pragma unroll
    for (int kk = 0; kk < 2; ++kk){
      int k8a = kk*4 + lk;
      short8 af[2];
      #pragma unroll
      for (int i = 0; i < 2; ++i){
        int ra = w*32 + i*16 + lr;
        af[i] = *(const short8*)&As[(ra*8 + (k8a ^ (ra & 7)))*8];
      }
      #pragma unroll
      for (int j = 0; j < 8; ++j){
        int rb = j*16 + lr;
        short8 bf = *(const short8*)&Bs[(rb*8 + (k8a ^ (rb & 7)))*8];
        acc[0][j] = MFMA_B16(af[0], bf, acc[0][j]);
        acc[1][j] = MFMA_B16(af[1], bf, acc[1][j]);
      }
    }
  }
  __syncthreads();
  #pragma unroll
  for (int i = 0; i < 2; ++i)
    #pragma unroll
    for (int j = 0; j < 8; ++j){
      int col = j*16 + lr;
      float bb = b1[n0 + col];
      #pragma unroll
      for (int q = 0; q < 4; ++q){
        int row = w*32 + i*16 + lk*4 + q;
        sm[row*128 + col] = f2bf(gelu_f(acc[i][j][q] + bb));
      }
    }
  __syncthreads();
  #pragma unroll
  for (int it = 0; it < 8; ++it){
    int e = t + it*256;
    int row = e >> 4, c8 = e & 15;
    *(short8*)&H[(size_t)(m0 + row)*1024 + n0 + c8*8] = *(const short8*)&sm[row*128 + c8*8];
  }
}

__global__ __launch_bounds__(256, 4) void k_gemm2(
  const unsigned short* __restrict__ A, const unsigned short* __restrict__ B,
  const float* __restrict__ b2v, const float* __restrict__ lsg,
  const unsigned short* __restrict__ xres, unsigned short* __restrict__ Y)
{
  __shared__ __align__(16) unsigned short sm[16384];
  unsigned short* As = sm;
  unsigned short* Bs = sm + 8192;
  int t = threadIdx.x, lane = t & 63, w = t >> 6;
  int lr = lane & 15, lk = lane >> 4;
  int p = blockIdx.x;
  int L = (p & 7) * 121 + (p >> 3);
  int m0 = (L >> 2) * 128, n0 = (L & 3) * 64;

  f32x4 acc[2][4];
  #pragma unroll
  for (int i = 0; i < 2; ++i)
    #pragma unroll
    for (int j = 0; j < 4; ++j) acc[i][j] = (f32x4){0,0,0,0};

  for (int ks = 0; ks < 16; ++ks){
    if (ks) __syncthreads();
    #pragma unroll
    for (int it = 0; it < 4; ++it){
      int j = t + it*256;
      int r = j >> 3, c = j & 7;
      int k8 = c ^ (r & 7);
      *(short8*)&As[j*8] = *(const short8*)&A[(size_t)(m0 + r)*1024 + ks*64 + k8*8];
    }
    #pragma unroll
    for (int it = 0; it < 2; ++it){
      int j = t + it*256;
      int r = j >> 3, c = j & 7;
      int k8 = c ^ (r & 7);
      *(short8*)&Bs[j*8] = *(const short8*)&B[(size_t)(n0 + r)*1024 + ks*64 + k8*8];
    }
    __syncthreads();
    #pragma unroll
    for (int kk = 0; kk < 2; ++kk){
      int k8a = kk*4 + lk;
      short8 af[2];
      #pragma unroll
      for (int i = 0; i < 2; ++i){
        int ra = w*32 + i*16 + lr;
        af[i] = *(const short8*)&As[(ra*8 + (k8a ^ (ra & 7)))*8];
      }
      #pragma unroll
      for (int j = 0; j < 4; ++j){
        int rb = j*16 + lr;
        short8 bf = *(const short8*)&Bs[(rb*8 + (k8a ^ (rb & 7)))*8];
        acc[0][j] = MFMA_B16(af[0], bf, acc[0][j]);
        acc[1][j] = MFMA_B16(af[1], bf, acc[1][j]);
      }
    }
  }
  __syncthreads();
  float* Cs = (float*)sm;
  #pragma unroll
  for (int i = 0; i < 2; ++i)
    #pragma unroll
    for (int j = 0; j < 4; ++j){
      int col = j*16 + lr;
      #pragma unroll
      for (int q = 0; q < 4; ++q){
        int row = w*32 + i*16 + lk*4 + q;
        Cs[row*64 + col] = acc[i][j][q];
      }
    }
  __syncthreads();
  #pragma unroll
  for (int it = 0; it < 8; ++it){
    int e4 = t + it*256;
    int row = e4 >> 4, c4 = (e4 & 15) * 4;
    float4 cv = *(const float4*)&Cs[row*64 + c4];
    size_t grow = (size_t)(m0 + row);
    ushort4 xr = *(const ushort4*)&xres[grow*256 + n0 + c4];
    float4 bb = *(const float4*)&b2v[n0 + c4];
    float4 gm = *(const float4*)&lsg[n0 + c4];
    ushort4 o;
    o.x = f2bf(fmaf(cv.x + bb.x, gm.x, bf2f(xr.x)));
    o.y = f2bf(fmaf(cv.y + bb.y, gm.y, bf2f(xr.y)));
    o.z = f2bf(fmaf(cv.z + bb.z, gm.z, bf2f(xr.z)));
    o.w = f2bf(fmaf(cv.w + bb.w, gm.w, bf2f(xr.w)));
    *(ushort4*)&Y[grow*256 + n0 + c4] = o;
  }
}

// ---------------- bn path: 1x1 conv 256->128 (MFMA) + gelu + gaussian reduce ----------
__global__ __launch_bounds__(256) void k_bnvec(
  const unsigned short* __restrict__ yb, const unsigned short* __restrict__ bnWb,
  const float* __restrict__ bn_b, const float* __restrict__ gbn, float* __restrict__ bn_vec)
{
  int n = blockIdx.x, t = threadIdx.x;
  int w = t >> 6, l = t & 63, lr = l & 15, lk = l >> 4;
  f32x4 acc[8][2];
  #pragma unroll
  for (int mt = 0; mt < 8; ++mt){ acc[mt][0] = (f32x4){0,0,0,0}; acc[mt][1] = (f32x4){0,0,0,0}; }

  #pragma unroll
  for (int ks = 0; ks < 8; ++ks){
    short8 b0 = *(const short8*)&bnWb[(size_t)(w*32 + lr)*256 + ks*32 + lk*8];
    short8 b1 = *(const short8*)&bnWb[(size_t)(w*32 + 16 + lr)*256 + ks*32 + lk*8];
    #pragma unroll
    for (int mt = 0; mt < 8; ++mt){
      int row = min(mt*16 + lr, 120);
      short8 a = *(const short8*)&yb[((size_t)n*121 + row)*256 + ks*32 + lk*8];
      acc[mt][0] = MFMA_B16(a, b0, acc[mt][0]);
      acc[mt][1] = MFMA_B16(a, b1, acc[mt][1]);
    }
  }

  float s0 = 0.f, s1 = 0.f;
  float bb0 = bn_b[w*32 + lr], bb1 = bn_b[w*32 + 16 + lr];
  #pragma unroll
  for (int mt = 0; mt < 8; ++mt)
    #pragma unroll
    for (int i = 0; i < 4; ++i){
      int row = mt*16 + lk*4 + i;
      if (row < 121){
        float g = gbn[row];
        s0 += g * gelu_f(acc[mt][0][i] + bb0);
        s1 += g * gelu_f(acc[mt][1][i] + bb1);
      }
    }
  s0 += __shfl_xor(s0, 16); s0 += __shfl_xor(s0, 32);
  s1 += __shfl_xor(s1, 16); s1 += __shfl_xor(s1, 32);
  if (lk == 0){
    bn_vec[n*128 + w*32 + lr] = s0;
    bn_vec[n*128 + w*32 + 16 + lr] = s1;
  }
}

// ---------------- head: 4 n per block ----------------
__global__ __launch_bounds__(256) void k_head(
  const float* __restrict__ bn_vec, const float* __restrict__ st_vec,
  const float* __restrict__ tr1_w, const float* __restrict__ tr1_b,
  const float* __restrict__ tr2_w, const float* __restrict__ tr2_b,
  const float* __restrict__ md_w, const float* __restrict__ md_b,
  const float* __restrict__ init_m,
  float* __restrict__ out)
{
  __shared__ float feat4[4*192];
  __shared__ float h14[4*256];
  __shared__ float h24[4*256];
  __shared__ float dlt4[4*961];
  __shared__ float yv4[4*961];
  int t = threadIdx.x;
  int n0 = blockIdx.x * 4;
  float* morph_out = out;
  float* delta_out = out + 984064;
  float* feat_out  = out + 1968128;

  for (int e = t; e < 4*192; e += 256){
    int ni = e / 192, j = e - ni*192;
    float v = (j < 128) ? bn_vec[(n0+ni)*128 + j] : st_vec[(n0+ni)*64 + j - 128];
    feat4[e] = v;
    feat_out[(size_t)(n0+ni)*192 + j] = v;
  }
  __syncthreads();
  {
    float a0 = tr1_b[t], a1 = a0, a2 = a0, a3 = a0;
    const float* wr = &tr1_w[t*192];
    for (int k = 0; k < 192; ++k){
      float wk = wr[k];
      a0 = fmaf(feat4[k],       wk, a0);
      a1 = fmaf(feat4[192 + k], wk, a1);
      a2 = fmaf(feat4[384 + k], wk, a2);
      a3 = fmaf(feat4[576 + k], wk, a3);
    }
    h14[t] = gelu_f(a0); h14[256 + t] = gelu_f(a1);
    h14[512 + t] = gelu_f(a2); h14[768 + t] = gelu_f(a3);
  }
  __syncthreads();
  {
    float a0 = tr2_b[t], a1 = a0, a2 = a0, a3 = a0;
    const float* wr = &tr2_w[t*256];
    for (int k = 0; k < 256; ++k){
      float wk = wr[k];
      a0 = fmaf(h14[k],       wk, a0);
      a1 = fmaf(h14[256 + k], wk, a1);
      a2 = fmaf(h14[512 + k], wk, a2);
      a3 = fmaf(h14[768 + k], wk, a3);
    }
    h24[t] = gelu_f(a0); h24[256 + t] = gelu_f(a1);
    h24[512 + t] = gelu_f(a2); h24[768 + t] = gelu_f(a3);
  }
  __syncthreads();
  for (int j = t; j < 961; j += 256){
    float b = md_b[j];
    float a0 = b, a1 = b, a2 = b, a3 = b;
    const float* wr = &md_w[(size_t)j*256];
    for (int k = 0; k < 256; ++k){
      float wk = wr[k];
      a0 = fmaf(h24[k],       wk, a0);
      a1 = fmaf(h24[256 + k], wk, a1);
      a2 = fmaf(h24[512 + k], wk, a2);
      a3 = fmaf(h24[768 + k], wk, a3);
    }
    float d0 = tanhf(a0), d1 = tanhf(a1), d2 = tanhf(a2), d3 = tanhf(a3);
    dlt4[j] = d0; dlt4[961 + j] = d1; dlt4[1922 + j] = d2; dlt4[2883 + j] = d3;
    delta_out[(size_t)(n0+0)*961 + j] = d0;
    delta_out[(size_t)(n0+1)*961 + j] = d1;
    delta_out[(size_t)(n0+2)*961 + j] = d2;
    delta_out[(size_t)(n0+3)*961 + j] = d3;
  }
  __syncthreads();

  int g = t >> 6, l64 = t & 63;
  int n = n0 + g;
  const float* im = &init_m[(size_t)n*961];
  float loc = 0.f;
  for (int j = l64; j < 961; j += 64) loc += fmaxf(im[j], 0.f);
  #pragma unroll
  for (int off = 32; off; off >>= 1) loc += __shfl_xor(loc, off);
  float s0 = loc + 1e-8f;
  float loc2 = 0.f;
  for (int j = l64; j < 961; j += 64){
    float imn = fmaxf(im[j], 0.f) / s0;
    float x = fmaxf(imn, 1e-8f);
    float base = x + logf(-expm1f(-x));
    float z = base + 1.5f * dlt4[g*961 + j];
    float y = fmaxf(z, 0.f) + log1pf(expf(-fabsf(z)));
    yv4[g*961 + j] = y;
    loc2 += y;
  }
  #pragma unroll
  for (int off = 32; off; off >>= 1) loc2 += __shfl_xor(loc2, off);
  float s1 = loc2 + 1e-8f;
  for (int j = l64; j < 961; j += 64)
    morph_out[(size_t)n*961 + j] = yv4[g*961 + j] / s1;
}

// ---------------- launch ----------------
extern "C" void kernel_launch(void* const* d_in, const int* in_sizes, int n_in,
                              void* d_out, int out_size, void* d_ws, size_t ws_size,
                              hipStream_t stream)
{
  const float* bott = (const float*)d_in[0];
  const float* vis  = (const float*)d_in[1];
  const float* pos  = (const float*)d_in[2];
  const float* initm= (const float*)d_in[3];
  const float* dw_w = (const float*)d_in[4];
  const float* dw_b = (const float*)d_in[5];
  const float* ln_g = (const float*)d_in[6];
  const float* ln_b = (const float*)d_in[7];
  const float* pw1_w= (const float*)d_in[8];
  const float* pw1_b= (const float*)d_in[9];
  const float* pw2_w= (const float*)d_in[10];
  const float* pw2_b= (const float*)d_in[11];
  const float* lsg  = (const float*)d_in[12];
  const float* bn_w = (const float*)d_in[13];
  const float* bn_b = (const float*)d_in[14];
  const float* st1_w= (const float*)d_in[15];
  const float* st1_b= (const float*)d_in[16];
  const float* st2_w= (const float*)d_in[17];
  const float* st2_b= (const float*)d_in[18];
  const float* tr1_w= (const float*)d_in[19];
  const float* tr1_b= (const float*)d_in[20];
  const float* tr2_w= (const float*)d_in[21];
  const float* tr2_b= (const float*)d_in[22];
  const float* md_w = (const float*)d_in[23];
  const float* md_b = (const float*)d_in[24];

  char* ws = (char*)d_ws;
  // Region A (126.9MB): v_win (st path) -> dcob (bnpre) -> Hq|yb (gemms)
  unsigned short* v_win = (unsigned short*)(ws);
  unsigned short* dcob  = (unsigned short*)(ws);
  unsigned short* Hq    = (unsigned short*)(ws);
  unsigned short* yb    = (unsigned short*)(ws + 63438848);
  // Regions B+C (126.9MB): x_bf | normb
  unsigned short* x_bf  = (unsigned short*)(ws + 126877696);
  unsigned short* normb = (unsigned short*)(ws + 190316544);
  char* S = ws + 253755392;
  float* st_vec = (float*)(S);
  float* bn_vec = (float*)(S + 262144);
  float* gbn    = (float*)(S + 786432);
  float* gst    = (float*)(S + 786944);
  unsigned short* W1b  = (unsigned short*)(S + 791040);
  unsigned short* W2b  = (unsigned short*)(S + 1315328);
  unsigned short* Wc1  = (unsigned short*)(S + 1839616);
  unsigned short* Wc2  = (unsigned short*)(S + 1913344);
  unsigned short* bnWb = (unsigned short*)(S + 1987072);

  hipMemsetAsync(st_vec, 0, 1024*64*sizeof(float), stream);
  k_gauss<<<1, 256, 0, stream>>>(gbn, gst);
  k_trans<<<256, 256, 0, stream>>>(pw1_w, pw2_w, bn_w, st1_w, st2_w, W1b, W2b, bnWb, Wc1, Wc2);

  // st path: gather (A = v_win), fused conv1+conv2 (band=6, 2 blk/CU) -> st_vec
  k_stg<<<2048, 256, 0, stream>>>(vis, pos, v_win);
  k_stconv<<<dim3(1024, 6), 512, 0, stream>>>(v_win, Wc1, st1_b, Wc2, st2_b, gst, st_vec);

  // bn pre (v_win dead: dcob -> A); 128-ch blocks
  k_bnpre<<<dim3(1024, 2), 512, 0, stream>>>(bott, pos, dw_w, dw_b, x_bf, dcob);
  k_ln<<<30976, 256, 0, stream>>>(dcob, ln_g, ln_b, normb);

  // MLP: 4 M-chunks of two GEMMs (dcob dead; A = Hq | yb)
  for (int q = 0; q < 4; ++q){
    size_t ro = (size_t)q * MQ;
    k_gemm1<<<1936, 256, 0, stream>>>(normb + ro*256, W1b, pw1_b, Hq);
    k_gemm2<<<968, 256, 0, stream>>>(Hq, W2b, pw2_b, lsg, x_bf + ro*256, yb + ro*256);
  }
  k_bnvec<<<1024, 256, 0, stream>>>(yb, bnWb, bn_b, gbn, bn_vec);

  // head
  k_head<<<256, 256, 0, stream>>>(bn_vec, st_vec, tr1_w, tr1_b, tr2_w, tr2_b,
                                  md_w, md_b, initm, (float*)d_out);
}

// Round 16
// 1217.223 us; speedup vs baseline: 1.2418x; 1.0321x over previous
//
#include <hip/hip_runtime.h>
#include <math.h>

// ---------------- constants ----------------
#define N_SRC 1024
#define VHW 1024
#define FHW 256
#define MQ2 61952           // M-chunk rows (123904/2) = 484 * 128

typedef __attribute__((ext_vector_type(8))) short short8;
typedef __attribute__((ext_vector_type(4))) float f32x4;

#define MFMA_B16(a,b,c) __builtin_amdgcn_mfma_f32_16x16x32_bf16((a),(b),(c),0,0,0)

__device__ __forceinline__ float gelu_f(float x){
  return 0.5f * x * (1.0f + erff(x * 0.70710678118654752440f));
}
__device__ __forceinline__ unsigned short f2bf(float f){
  union { float f; unsigned u; } x; x.f = f;
  unsigned r = x.u + 0x7fffu + ((x.u >> 16) & 1u);
  return (unsigned short)(r >> 16);
}
__device__ __forceinline__ float bf2f(unsigned short h){
  union { unsigned u; float f; } x; x.u = ((unsigned)h) << 16;
  return x.f;
}

// ---------------- gaussian tables ----------------
__global__ void k_gauss(float* __restrict__ gbn, float* __restrict__ gst){
  __shared__ double red[256];
  int t = threadIdx.x;
  {
    double v = 0.0;
    if (t < 121){
      int r = t / 11, c = t % 11;
      double y = -1.0 + 2.0 * (double)r / 10.0;
      double x = -1.0 + 2.0 * (double)c / 10.0;
      v = exp(-(x*x + y*y) / (2.0 * 0.4 * 0.4));
    }
    red[t] = v; __syncthreads();
    for (int s = 128; s > 0; s >>= 1){ if (t < s) red[t] += red[t+s]; __syncthreads(); }
    double sum = red[0];
    __syncthreads();
    if (t < 121) gbn[t] = (float)(v / sum);
    __syncthreads();
  }
  {
    double vals[4]; double loc = 0.0;
    #pragma unroll
    for (int i = 0; i < 4; ++i){
      int j = t + 256*i;
      double v = 0.0;
      if (j < 961){
        int r = j / 31, c = j % 31;
        double y = -1.0 + 2.0 * (double)r / 30.0;
        double x = -1.0 + 2.0 * (double)c / 30.0;
        v = exp(-(x*x + y*y) / (2.0 * 0.4 * 0.4));
      }
      vals[i] = v; loc += v;
    }
    red[t] = loc; __syncthreads();
    for (int s = 128; s > 0; s >>= 1){ if (t < s) red[t] += red[t+s]; __syncthreads(); }
    double sum = red[0];
    __syncthreads();
    #pragma unroll
    for (int i = 0; i < 4; ++i){
      int j = t + 256*i;
      if (j < 961) gst[j] = (float)(vals[i] / sum);
    }
  }
}

// ---------------- weight conversion ----------------
__global__ void k_trans(const float* __restrict__ pw1_w, const float* __restrict__ pw2_w,
                        const float* __restrict__ bn_w,
                        const float* __restrict__ st1_w, const float* __restrict__ st2_w,
                        unsigned short* __restrict__ W1b, unsigned short* __restrict__ W2b,
                        unsigned short* __restrict__ bnWb,
                        unsigned short* __restrict__ Wc1, unsigned short* __restrict__ Wc2){
  int stride = gridDim.x * blockDim.x;
  int i0 = blockIdx.x * blockDim.x + threadIdx.x;
  for (int e = i0; e < 256*1024; e += stride) W1b[e] = f2bf(pw1_w[e]);
  for (int e = i0; e < 256*1024; e += stride) W2b[e] = f2bf(pw2_w[e]);
  for (int e = i0; e < 128*256; e += stride) bnWb[e] = f2bf(bn_w[e]);
  for (int e = i0; e < 64*576; e += stride){
    int co = e / 576, r = e % 576, d = r >> 6, ci = r & 63;
    Wc1[e] = f2bf(st1_w[(co*64 + ci)*9 + d]);
    Wc2[e] = f2bf(st2_w[(co*64 + ci)*9 + d]);
  }
}

// =======================================================================
// st path:
//   k_stg    : wave-coalesced gather vis -> v_win bf16 plane-major [8cg][n*961][8]
//   k_stconv : fused conv1+conv2, granule-major LDS, band=16, dual-B
//              (round-11 measured-best config; As stride padded 660->662)
// =======================================================================

__global__ __launch_bounds__(256) void k_stg(
    const float* __restrict__ vis, const float* __restrict__ pos,
    unsigned short* __restrict__ v_win)
{
  int b = blockIdx.x;
  int n = b >> 1, h = b & 1;
  float px = pos[2*n], py = pos[2*n + 1];
  int e0 = h * 3844;                      // 961*8/2
  for (int e = e0 + threadIdx.x; e < e0 + 3844; e += 256){
    int cg = e / 961, p = e - cg*961;
    int r = p / 31, c = p - r*31;
    float xsf = fminf(fmaxf(px + (float)(c - 15), 0.f), 1023.f);
    float ysf = fminf(fmaxf(py + (float)(r - 15), 0.f), 1023.f);
    int x0 = min((int)xsf, 1022);
    int y0 = min((int)ysf, 1022);
    float wx = xsf - (float)x0, wy = ysf - (float)y0;
    float w00 = (1.f-wy)*(1.f-wx), w01 = (1.f-wy)*wx;
    float w10 = wy*(1.f-wx),       w11 = wy*wx;
    size_t off = (size_t)y0*VHW + x0;
    const float* bp = vis + (size_t)(cg*8)*(VHW*VHW) + off;
    short8 v;
    #pragma unroll
    for (int i = 0; i < 8; ++i){
      const float* bb = bp + (size_t)i*(VHW*VHW);
      v[i] = (short)f2bf(bb[0]*w00 + bb[1]*w01 + bb[VHW]*w10 + bb[VHW+1]*w11);
    }
    *(short8*)&v_win[((size_t)cg*(1024*961) + (size_t)n*961 + p)*8] = v;
  }
}

// granule-major conv, dual B arrays (32 co per wave); NP = granule stride
template<int NP>
__device__ __forceinline__ void conv_tiles_g2(
    const unsigned short* __restrict__ in_t, const short8* B0, const short8* B1,
    int pb0, int pb1, int lk, f32x4& a00, f32x4& a01, f32x4& a10, f32x4& a11)
{
  const unsigned short* a0p = in_t + (lk*NP + pb0)*8;
  const unsigned short* a1p = in_t + (lk*NP + pb1)*8;
  #pragma unroll
  for (int ks = 0; ks < 18; ++ks){
    const int d = ks >> 1;
    const int dy = d / 3, dx = d - dy*3;
    const int off = (((ks & 1) ? 4*NP : 0) + dy*33 + dx) * 8;
    short8 A0 = *(const short8*)&a0p[off];
    short8 A1 = *(const short8*)&a1p[off];
    a00 = MFMA_B16(A0, B0[ks], a00);
    a01 = MFMA_B16(A0, B1[ks], a01);
    a10 = MFMA_B16(A1, B0[ks], a10);
    a11 = MFMA_B16(A1, B1[ks], a11);
  }
}

#define BANDR 16
#define NPA_P 660   // As positions used: 20 rows x 33
#define NPA_S 662   // As granule stride (662*4 mod 32 = 24 -> lk phases 0/24/16/8)
#define NPB_S 594   // Bs positions & stride: 18 rows x 33 (594*4 mod 32 = 8 -> 0/8/16/24)

__global__ __launch_bounds__(512, 1) void k_stconv(
    const unsigned short* __restrict__ v_win,
    const unsigned short* __restrict__ Wc1, const float* __restrict__ st1_b,
    const unsigned short* __restrict__ Wc2, const float* __restrict__ st2_b,
    const float* __restrict__ gst, float* __restrict__ st_vec)
{
  __shared__ __align__(16) unsigned short As[NPA_S*64];  // 84,736 B
  __shared__ __align__(16) unsigned short Bs[NPB_S*64];  // 76,032 B
  int n = blockIdx.x, band = blockIdx.y;
  int t = threadIdx.x;
  int w = t >> 6, l = t & 63, lr = l & 15, lk = l >> 4;
  int co0 = (w & 1) * 32;        // 2-way co split: two 16-co tiles per wave
  int mh = w >> 1;               // 4-way m split
  int ybaseV = band*BANDR - 2;
  int ybaseG = band*BANDR - 1;
  int rows_out = band ? 15 : 16;

  // stage As (granule-major, zero-pad halo); lanes consecutive p
  #pragma unroll
  for (int cg = 0; cg < 8; ++cg){
    for (int p = t; p < NPA_P; p += 512){
      int gr = p / 33, gc = p - gr*33;
      int yy = ybaseV + gr, xx = gc - 1;
      short8 v = {0,0,0,0,0,0,0,0};
      if (yy >= 0 && yy < 31 && xx >= 0 && xx < 31)
        v = *(const short8*)&v_win[((size_t)cg*(1024*961) + (size_t)n*961 + yy*31 + xx)*8];
      *(short8*)&As[(cg*NPA_S + p)*8] = v;
    }
  }
  // zero Bs
  {
    short8 z = {0,0,0,0,0,0,0,0};
    for (int c = t; c < NPB_S*8; c += 512)
      *(short8*)&Bs[c*8] = z;
  }
  __syncthreads();

  // ---- phase 1: conv1 + gelu -> Bs (18 g1 rows x 31 cols; invalid rows stay 0)
  {
    short8 B0[18], B1[18];
    #pragma unroll
    for (int ks = 0; ks < 18; ++ks){
      B0[ks] = *(const short8*)&Wc1[(co0 + lr)*576 + ks*32 + lk*8];
      B1[ks] = *(const short8*)&Wc1[(co0 + 16 + lr)*576 + ks*32 + lk*8];
    }
    const int npos1 = 18*31;           // 558
    const int ntiles1 = 35;
    int mstart = mh * 10;
    int mend = min(mstart + 10, ntiles1);
    float bc0 = st1_b[co0 + lr], bc1 = st1_b[co0 + 16 + lr];
    int c0 = co0 + lr, c1 = co0 + 16 + lr;

    for (int mt = mstart; mt < mend; mt += 2){
      int s0 = min(mt*16 + lr, npos1 - 1);
      int s1 = min(mt*16 + 16 + lr, npos1 - 1);
      int ly0 = s0 / 31, x0p = s0 - ly0*31;
      int ly1 = s1 / 31, x1p = s1 - ly1*31;
      int pb0 = ly0*33 + x0p, pb1 = ly1*33 + x1p;
      f32x4 a00 = {0,0,0,0}, a01 = {0,0,0,0}, a10 = {0,0,0,0}, a11 = {0,0,0,0};
      conv_tiles_g2<NPA_S>(As, B0, B1, pb0, pb1, lk, a00, a01, a10, a11);
      #pragma unroll
      for (int i = 0; i < 4; ++i){
        int spo = mt*16 + lk*4 + i;
        if (spo < npos1){
          int ly = spo / 31, xx = spo - ly*31;
          int yy1 = ybaseG + ly;
          if (yy1 >= 0 && yy1 <= 30){
            int pB = ly*33 + xx + 1;
            Bs[((c0 >> 3)*NPB_S + pB)*8 + (c0 & 7)] = f2bf(gelu_f(a00[i] + bc0));
            Bs[((c1 >> 3)*NPB_S + pB)*8 + (c1 & 7)] = f2bf(gelu_f(a01[i] + bc1));
          }
        }
        int sp1 = spo + 16;
        if (sp1 < npos1 && mt + 1 < mend){
          int ly = sp1 / 31, xx = sp1 - ly*31;
          int yy1 = ybaseG + ly;
          if (yy1 >= 0 && yy1 <= 30){
            int pB = ly*33 + xx + 1;
            Bs[((c0 >> 3)*NPB_S + pB)*8 + (c0 & 7)] = f2bf(gelu_f(a10[i] + bc0));
            Bs[((c1 >> 3)*NPB_S + pB)*8 + (c1 & 7)] = f2bf(gelu_f(a11[i] + bc1));
          }
        }
      }
    }
  }
  __syncthreads();

  // ---- phase 2: conv2 + gelu + gaussian reduce -> st_vec
  {
    short8 B0[18], B1[18];
    #pragma unroll
    for (int ks = 0; ks < 18; ++ks){
      B0[ks] = *(const short8*)&Wc2[(co0 + lr)*576 + ks*32 + lk*8];
      B1[ks] = *(const short8*)&Wc2[(co0 + 16 + lr)*576 + ks*32 + lk*8];
    }
    int npos = rows_out * 31;
    int ntiles = (npos + 15) >> 4;
    int mstart = mh * 8;
    int mend = min(mstart + 8, ntiles);
    float bc0 = st2_b[co0 + lr], bc1 = st2_b[co0 + 16 + lr];
    float vacc0 = 0.f, vacc1 = 0.f;

    for (int mt = mstart; mt < mend; mt += 2){
      int s0 = min(mt*16 + lr, npos - 1);
      int s1 = min(mt*16 + 16 + lr, npos - 1);
      int ly0 = s0 / 31, x0p = s0 - ly0*31;
      int ly1 = s1 / 31, x1p = s1 - ly1*31;
      int pb0 = ly0*33 + x0p, pb1 = ly1*33 + x1p;
      f32x4 a00 = {0,0,0,0}, a01 = {0,0,0,0}, a10 = {0,0,0,0}, a11 = {0,0,0,0};
      conv_tiles_g2<NPB_S>(Bs, B0, B1, pb0, pb1, lk, a00, a01, a10, a11);
      #pragma unroll
      for (int i = 0; i < 4; ++i){
        int spo = mt*16 + lk*4 + i;
        if (spo < npos){
          int ly = spo / 31, xx = spo - ly*31;
          float wt = gst[(band*BANDR + ly)*31 + xx];
          vacc0 += wt * gelu_f(a00[i] + bc0);
          vacc1 += wt * gelu_f(a01[i] + bc1);
        }
        int sp1 = spo + 16;
        if (sp1 < npos && mt + 1 < mend){
          int ly = sp1 / 31, xx = sp1 - ly*31;
          float wt = gst[(band*BANDR + ly)*31 + xx];
          vacc0 += wt * gelu_f(a10[i] + bc0);
          vacc1 += wt * gelu_f(a11[i] + bc1);
        }
      }
    }
    vacc0 += __shfl_xor(vacc0, 16); vacc0 += __shfl_xor(vacc0, 32);
    vacc1 += __shfl_xor(vacc1, 16); vacc1 += __shfl_xor(vacc1, 32);
    if (lk == 0){
      atomicAdd(&st_vec[n*64 + co0 + lr], vacc0);
      atomicAdd(&st_vec[n*64 + co0 + 16 + lr], vacc1);
    }
  }
}

// ---------------- bn path: fused gather + depthwise 7x7, 128-ch blocks ----------
__global__ __launch_bounds__(512, 4) void k_bnpre(
  const float* __restrict__ bott, const float* __restrict__ pos,
  const float* __restrict__ dw_w, const float* __restrict__ dw_b,
  unsigned short* __restrict__ x_bf, unsigned short* __restrict__ dcob)
{
  __shared__ float xt[128*123];
  __shared__ float wt4[121*4];
  __shared__ int   wo[121];
  int n = blockIdx.x, ch0 = blockIdx.y * 128;
  int t = threadIdx.x;
  float pbx = (pos[2*n]   + 0.5f)*0.25f - 0.5f;
  float pby = (pos[2*n+1] + 0.5f)*0.25f - 0.5f;

  if (t < 121){
    int r = t / 11, c = t - r*11;
    float xsf = fminf(fmaxf(pbx + (float)(c-5), 0.f), 255.f);
    float ysf = fminf(fmaxf(pby + (float)(r-5), 0.f), 255.f);
    int x0 = min((int)xsf, 254);
    int y0 = min((int)ysf, 254);
    float wx = xsf - (float)x0, wy = ysf - (float)y0;
    wo[t] = y0*FHW + x0;
    wt4[t*4+0] = (1.f-wy)*(1.f-wx);
    wt4[t*4+1] = (1.f-wy)*wx;
    wt4[t*4+2] = wy*(1.f-wx);
    wt4[t*4+3] = wy*wx;
  }
  __syncthreads();

  for (int e = t; e < 128*121; e += 512){
    int ch = e / 121, p = e - ch*121;
    const float* b = bott + (size_t)(ch0 + ch)*(FHW*FHW) + wo[p];
    float4 w = *(const float4*)&wt4[p*4];
    xt[ch*123 + p] = b[0]*w.x + b[1]*w.y + b[FHW]*w.z + b[FHW+1]*w.w;
  }
  __syncthreads();

  for (int e = t; e < 121*64; e += 512){
    int row = e >> 6, cp = (e & 63) << 1;
    float v0 = xt[cp*123 + row], v1 = xt[(cp+1)*123 + row];
    unsigned pk = (unsigned)f2bf(v0) | ((unsigned)f2bf(v1) << 16);
    *(unsigned*)&x_bf[(((size_t)n*121 + row) << 8) + ch0 + cp] = pk;
  }

  int ch = t & 127, part = t >> 7;
  float w[49];
  #pragma unroll
  for (int k = 0; k < 49; ++k) w[k] = dw_w[(ch0 + ch)*49 + k];
  float bias = dw_b[ch0 + ch];
  const float* xc = &xt[ch*123];
  for (int sp = part; sp < 121; sp += 4){
    int r = sp / 11, c = sp - r*11;
    float a = bias;
    #pragma unroll
    for (int dy = 0; dy < 7; ++dy){
      int ry = r + dy - 3;
      bool okr = (ry >= 0) && (ry < 11);
      #pragma unroll
      for (int dx = 0; dx < 7; ++dx){
        int cx = c + dx - 3;
        float xv = (okr && cx >= 0 && cx < 11) ? xc[ry*11 + cx] : 0.f;
        a = fmaf(xv, w[dy*7 + dx], a);
      }
    }
    dcob[(((size_t)n*121 + sp) << 8) + ch0 + ch] = f2bf(a);
  }
}

// ---------------- bn path: layernorm bf16 -> bf16 ----------------
__global__ __launch_bounds__(256) void k_ln(
  const unsigned short* __restrict__ dcob, const float* __restrict__ ln_g, const float* __restrict__ ln_b,
  unsigned short* __restrict__ normb)
{
  int m = blockIdx.x*4 + (threadIdx.x >> 6);
  int lane = threadIdx.x & 63;
  ushort4 raw = *(const ushort4*)&dcob[(size_t)m*256 + lane*4];
  float4 v = { bf2f(raw.x), bf2f(raw.y), bf2f(raw.z), bf2f(raw.w) };
  float s  = v.x+v.y+v.z+v.w;
  float ss = v.x*v.x + v.y*v.y + v.z*v.z + v.w*v.w;
  #pragma unroll
  for (int off = 32; off; off >>= 1){ s += __shfl_xor(s, off); ss += __shfl_xor(ss, off); }
  float mu  = s * 0.00390625f;
  float var = ss * 0.00390625f - mu*mu;
  float rstd = 1.0f / sqrtf(var + 1e-6f);
  float4 g = *(const float4*)&ln_g[lane*4];
  float4 b = *(const float4*)&ln_b[lane*4];
  ushort4 o;
  o.x = f2bf((v.x-mu)*rstd*g.x + b.x);
  o.y = f2bf((v.y-mu)*rstd*g.y + b.y);
  o.z = f2bf((v.z-mu)*rstd*g.z + b.z);
  o.w = f2bf((v.w-mu)*rstd*g.w + b.w);
  *(ushort4*)&normb[(size_t)m*256 + lane*4] = o;
}

// =======================================================================
// MLP as two m97-style GEMMs over M-chunks of 61952 rows (2 chunks).
// =======================================================================

// GEMM1: H = gelu(X . W1^T + b1). Tile 128x128, BK=64. grid 3872 = 484m x 8n.
__global__ __launch_bounds__(256, 3) void k_gemm1(
  const unsigned short* __restrict__ A, const unsigned short* __restrict__ B,
  const float* __restrict__ b1, unsigned short* __restrict__ H)
{
  __shared__ __align__(16) unsigned short sm[16384];
  unsigned short* As = sm;
  unsigned short* Bs = sm + 8192;
  int t = threadIdx.x, lane = t & 63, w = t >> 6;
  int lr = lane & 15, lk = lane >> 4;
  int p = blockIdx.x;
  int L = (p & 7) * 484 + (p >> 3);
  int m0 = (L >> 3) * 128, n0 = (L & 7) * 128;

  f32x4 acc[2][8];
  #pragma unroll
  for (int i = 0; i < 2; ++i)
    #pragma unroll
    for (int j = 0; j < 8; ++j) acc[i][j] = (f32x4){0,0,0,0};

  for (int ks = 0; ks < 4; ++ks){
    if (ks) __syncthreads();
    #pragma unroll
    for (int it = 0; it < 4; ++it){
      int j = t + it*256;
      int r = j >> 3, c = j & 7;
      int k8 = c ^ (r & 7);
      *(short8*)&As[j*8] = *(const short8*)&A[(size_t)(m0 + r)*256 + ks*64 + k8*8];
      *(short8*)&Bs[j*8] = *(const short8*)&B[(size_t)(n0 + r)*256 + ks*64 + k8*8];
    }
    __syncthreads();
    #pragma unroll
    for (int kk = 0; kk < 2; ++kk){
      int k8a = kk*4 + lk;
      short8 af[2];
      #pragma unroll
      for (int i = 0; i < 2; ++i){
        int ra = w*32 + i*16 + lr;
        af[i] = *(const short8*)&As[(ra*8 + (k8a ^ (ra & 7)))*8];
      }
      #pragma unroll
      for (int j = 0; j < 8; ++j){
        int rb = j*16 + lr;
        short8 bf = *(const short8*)&Bs[(rb*8 + (k8a ^ (rb & 7)))*8];
        acc[0][j] = MFMA_B16(af[0], bf, acc[0][j]);
        acc[1][j] = MFMA_B16(af[1], bf, acc[1][j]);
      }
    }
  }
  __syncthreads();
  #pragma unroll
  for (int i = 0; i < 2; ++i)
    #pragma unroll
    for (int j = 0; j < 8; ++j){
      int col = j*16 + lr;
      float bb = b1[n0 + col];
      #pragma unroll
      for (int q = 0; q < 4; ++q){
        int row = w*32 + i*16 + lk*4 + q;
        sm[row*128 + col] = f2bf(gelu_f(acc[i][j][q] + bb));
      }
    }
  __syncthreads();
  #pragma unroll
  for (int it = 0; it < 8; ++it){
    int e = t + it*256;
    int row = e >> 4, c8 = e & 15;
    *(short8*)&H[(size_t)(m0 + row)*1024 + n0 + c8*8] = *(const short8*)&sm[row*128 + c8*8];
  }
}

// GEMM2: Y = (H . W2^T + b2)*gamma + xres. Tile 128x64, BK=64. grid 1936 = 484m x 4n.
__global__ __launch_bounds__(256, 4) void k_gemm2(
  const unsigned short* __restrict__ A, const unsigned short* __restrict__ B,
  const float* __restrict__ b2v, const float* __restrict__ lsg,
  const unsigned short* __restrict__ xres, unsigned short* __restrict__ Y)
{
  __shared__ __align__(16) unsigned short sm[16384];
  unsigned short* As = sm;
  unsigned short* Bs = sm + 8192;
  int t = threadIdx.x, lane = t & 63, w = t >> 6;
  int lr = lane & 15, lk = lane >> 4;
  int p = blockIdx.x;
  int L = (p & 7) * 242 + (p >> 3);
  int m0 = (L >> 2) * 128, n0 = (L & 3) * 64;

  f32x4 acc[2][4];
  #pragma unroll
  for (int i = 0; i < 2; ++i)
    #pragma unroll
    for (int j = 0; j < 4; ++j) acc[i][j] = (f32x4){0,0,0,0};

  for (int ks = 0; ks < 16; ++ks){
    if (ks) __syncthreads();
    #pragma unroll
    for (int it = 0; it < 4; ++it){
      int j = t + it*256;
      int r = j >> 3, c = j & 7;
      int k8 = c ^ (r & 7);
      *(short8*)&As[j*8] = *(const short8*)&A[(size_t)(m0 + r)*1024 + ks*64 + k8*8];
    }
    #pragma unroll
    for (int it = 0; it < 2; ++it){
      int j = t + it*256;
      int r = j >> 3, c = j & 7;
      int k8 = c ^ (r & 7);
      *(short8*)&Bs[j*8] = *(const short8*)&B[(size_t)(n0 + r)*1024 + ks*64 + k8*8];
    }
    __syncthreads();
    #pragma unroll
    for (int kk = 0; kk < 2; ++kk){
      int k8a = kk*4 + lk;
      short8 af[2];
      #pragma unroll
      for (int i = 0; i < 2; ++i){
        int ra = w*32 + i*16 + lr;
        af[i] = *(const short8*)&As[(ra*8 + (k8a ^ (ra & 7)))*8];
      }
      #pragma unroll
      for (int j = 0; j < 4; ++j){
        int rb = j*16 + lr;
        short8 bf = *(const short8*)&Bs[(rb*8 + (k8a ^ (rb & 7)))*8];
        acc[0][j] = MFMA_B16(af[0], bf, acc[0][j]);
        acc[1][j] = MFMA_B16(af[1], bf, acc[1][j]);
      }
    }
  }
  __syncthreads();
  float* Cs = (float*)sm;
  #pragma unroll
  for (int i = 0; i < 2; ++i)
    #pragma unroll
    for (int j = 0; j < 4; ++j){
      int col = j*16 + lr;
      #pragma unroll
      for (int q = 0; q < 4; ++q){
        int row = w*32 + i*16 + lk*4 + q;
        Cs[row*64 + col] = acc[i][j][q];
      }
    }
  __syncthreads();
  #pragma unroll
  for (int it = 0; it < 8; ++it){
    int e4 = t + it*256;
    int row = e4 >> 4, c4 = (e4 & 15) * 4;
    float4 cv = *(const float4*)&Cs[row*64 + c4];
    size_t grow = (size_t)(m0 + row);
    ushort4 xr = *(const ushort4*)&xres[grow*256 + n0 + c4];
    float4 bb = *(const float4*)&b2v[n0 + c4];
    float4 gm = *(const float4*)&lsg[n0 + c4];
    ushort4 o;
    o.x = f2bf(fmaf(cv.x + bb.x, gm.x, bf2f(xr.x)));
    o.y = f2bf(fmaf(cv.y + bb.y, gm.y, bf2f(xr.y)));
    o.z = f2bf(fmaf(cv.z + bb.z, gm.z, bf2f(xr.z)));
    o.w = f2bf(fmaf(cv.w + bb.w, gm.w, bf2f(xr.w)));
    *(ushort4*)&Y[grow*256 + n0 + c4] = o;
  }
}

// ---------------- bn path: 1x1 conv 256->128 (MFMA) + gelu + gaussian reduce ----------
__global__ __launch_bounds__(256) void k_bnvec(
  const unsigned short* __restrict__ yb, const unsigned short* __restrict__ bnWb,
  const float* __restrict__ bn_b, const float* __restrict__ gbn, float* __restrict__ bn_vec)
{
  int n = blockIdx.x, t = threadIdx.x;
  int w = t >> 6, l = t & 63, lr = l & 15, lk = l >> 4;
  f32x4 acc[8][2];
  #pragma unroll
  for (int mt = 0; mt < 8; ++mt){ acc[mt][0] = (f32x4){0,0,0,0}; acc[mt][1] = (f32x4){0,0,0,0}; }

  #pragma unroll
  for (int ks = 0; ks < 8; ++ks){
    short8 b0 = *(const short8*)&bnWb[(size_t)(w*32 + lr)*256 + ks*32 + lk*8];
    short8 b1 = *(const short8*)&bnWb[(size_t)(w*32 + 16 + lr)*256 + ks*32 + lk*8];
    #pragma unroll
    for (int mt = 0; mt < 8; ++mt){
      int row = min(mt*16 + lr, 120);
      short8 a = *(const short8*)&yb[((size_t)n*121 + row)*256 + ks*32 + lk*8];
      acc[mt][0] = MFMA_B16(a, b0, acc[mt][0]);
      acc[mt][1] = MFMA_B16(a, b1, acc[mt][1]);
    }
  }

  float s0 = 0.f, s1 = 0.f;
  float bb0 = bn_b[w*32 + lr], bb1 = bn_b[w*32 + 16 + lr];
  #pragma unroll
  for (int mt = 0; mt < 8; ++mt)
    #pragma unroll
    for (int i = 0; i < 4; ++i){
      int row = mt*16 + lk*4 + i;
      if (row < 121){
        float g = gbn[row];
        s0 += g * gelu_f(acc[mt][0][i] + bb0);
        s1 += g * gelu_f(acc[mt][1][i] + bb1);
      }
    }
  s0 += __shfl_xor(s0, 16); s0 += __shfl_xor(s0, 32);
  s1 += __shfl_xor(s1, 16); s1 += __shfl_xor(s1, 32);
  if (lk == 0){
    bn_vec[n*128 + w*32 + lr] = s0;
    bn_vec[n*128 + w*32 + 16 + lr] = s1;
  }
}

// ---------------- head: 4 n per block ----------------
__global__ __launch_bounds__(256) void k_head(
  const float* __restrict__ bn_vec, const float* __restrict__ st_vec,
  const float* __restrict__ tr1_w, const float* __restrict__ tr1_b,
  const float* __restrict__ tr2_w, const float* __restrict__ tr2_b,
  const float* __restrict__ md_w, const float* __restrict__ md_b,
  const float* __restrict__ init_m,
  float* __restrict__ out)
{
  __shared__ float feat4[4*192];
  __shared__ float h14[4*256];
  __shared__ float h24[4*256];
  __shared__ float dlt4[4*961];
  __shared__ float yv4[4*961];
  int t = threadIdx.x;
  int n0 = blockIdx.x * 4;
  float* morph_out = out;
  float* delta_out = out + 984064;
  float* feat_out  = out + 1968128;

  for (int e = t; e < 4*192; e += 256){
    int ni = e / 192, j = e - ni*192;
    float v = (j < 128) ? bn_vec[(n0+ni)*128 + j] : st_vec[(n0+ni)*64 + j - 128];
    feat4[e] = v;
    feat_out[(size_t)(n0+ni)*192 + j] = v;
  }
  __syncthreads();
  {
    float a0 = tr1_b[t], a1 = a0, a2 = a0, a3 = a0;
    const float* wr = &tr1_w[t*192];
    for (int k = 0; k < 192; ++k){
      float wk = wr[k];
      a0 = fmaf(feat4[k],       wk, a0);
      a1 = fmaf(feat4[192 + k], wk, a1);
      a2 = fmaf(feat4[384 + k], wk, a2);
      a3 = fmaf(feat4[576 + k], wk, a3);
    }
    h14[t] = gelu_f(a0); h14[256 + t] = gelu_f(a1);
    h14[512 + t] = gelu_f(a2); h14[768 + t] = gelu_f(a3);
  }
  __syncthreads();
  {
    float a0 = tr2_b[t], a1 = a0, a2 = a0, a3 = a0;
    const float* wr = &tr2_w[t*256];
    for (int k = 0; k < 256; ++k){
      float wk = wr[k];
      a0 = fmaf(h14[k],       wk, a0);
      a1 = fmaf(h14[256 + k], wk, a1);
      a2 = fmaf(h14[512 + k], wk, a2);
      a3 = fmaf(h14[768 + k], wk, a3);
    }
    h24[t] = gelu_f(a0); h24[256 + t] = gelu_f(a1);
    h24[512 + t] = gelu_f(a2); h24[768 + t] = gelu_f(a3);
  }
  __syncthreads();
  for (int j = t; j < 961; j += 256){
    float b = md_b[j];
    float a0 = b, a1 = b, a2 = b, a3 = b;
    const float* wr = &md_w[(size_t)j*256];
    for (int k = 0; k < 256; ++k){
      float wk = wr[k];
      a0 = fmaf(h24[k],       wk, a0);
      a1 = fmaf(h24[256 + k], wk, a1);
      a2 = fmaf(h24[512 + k], wk, a2);
      a3 = fmaf(h24[768 + k], wk, a3);
    }
    float d0 = tanhf(a0), d1 = tanhf(a1), d2 = tanhf(a2), d3 = tanhf(a3);
    dlt4[j] = d0; dlt4[961 + j] = d1; dlt4[1922 + j] = d2; dlt4[2883 + j] = d3;
    delta_out[(size_t)(n0+0)*961 + j] = d0;
    delta_out[(size_t)(n0+1)*961 + j] = d1;
    delta_out[(size_t)(n0+2)*961 + j] = d2;
    delta_out[(size_t)(n0+3)*961 + j] = d3;
  }
  __syncthreads();

  int g = t >> 6, l64 = t & 63;
  int n = n0 + g;
  const float* im = &init_m[(size_t)n*961];
  float loc = 0.f;
  for (int j = l64; j < 961; j += 64) loc += fmaxf(im[j], 0.f);
  #pragma unroll
  for (int off = 32; off; off >>= 1) loc += __shfl_xor(loc, off);
  float s0 = loc + 1e-8f;
  float loc2 = 0.f;
  for (int j = l64; j < 961; j += 64){
    float imn = fmaxf(im[j], 0.f) / s0;
    float x = fmaxf(imn, 1e-8f);
    float base = x + logf(-expm1f(-x));
    float z = base + 1.5f * dlt4[g*961 + j];
    float y = fmaxf(z, 0.f) + log1pf(expf(-fabsf(z)));
    yv4[g*961 + j] = y;
    loc2 += y;
  }
  #pragma unroll
  for (int off = 32; off; off >>= 1) loc2 += __shfl_xor(loc2, off);
  float s1 = loc2 + 1e-8f;
  for (int j = l64; j < 961; j += 64)
    morph_out[(size_t)n*961 + j] = yv4[g*961 + j] / s1;
}

// ---------------- launch ----------------
extern "C" void kernel_launch(void* const* d_in, const int* in_sizes, int n_in,
                              void* d_out, int out_size, void* d_ws, size_t ws_size,
                              hipStream_t stream)
{
  const float* bott = (const float*)d_in[0];
  const float* vis  = (const float*)d_in[1];
  const float* pos  = (const float*)d_in[2];
  const float* initm= (const float*)d_in[3];
  const float* dw_w = (const float*)d_in[4];
  const float* dw_b = (const float*)d_in[5];
  const float* ln_g = (const float*)d_in[6];
  const float* ln_b = (const float*)d_in[7];
  const float* pw1_w= (const float*)d_in[8];
  const float* pw1_b= (const float*)d_in[9];
  const float* pw2_w= (const float*)d_in[10];
  const float* pw2_b= (const float*)d_in[11];
  const float* lsg  = (const float*)d_in[12];
  const float* bn_w = (const float*)d_in[13];
  const float* bn_b = (const float*)d_in[14];
  const float* st1_w= (const float*)d_in[15];
  const float* st1_b= (const float*)d_in[16];
  const float* st2_w= (const float*)d_in[17];
  const float* st2_b= (const float*)d_in[18];
  const float* tr1_w= (const float*)d_in[19];
  const float* tr1_b= (const float*)d_in[20];
  const float* tr2_w= (const float*)d_in[21];
  const float* tr2_b= (const float*)d_in[22];
  const float* md_w = (const float*)d_in[23];
  const float* md_b = (const float*)d_in[24];

  char* ws = (char*)d_ws;
  // Region A (126.9MB): v_win (st path) -> dcob (bnpre) -> Hq (full region, per chunk)
  unsigned short* v_win = (unsigned short*)(ws);
  unsigned short* dcob  = (unsigned short*)(ws);
  unsigned short* Hq    = (unsigned short*)(ws);
  // Region B (63.4MB): x_bf residual
  unsigned short* x_bf  = (unsigned short*)(ws + 126877696);
  // Region C (63.4MB): normb; yb ALIASES normb (chunk-k gemm2 writes rows the
  // chunk-k gemm1 has already consumed -- serial stream guarantees ordering)
  unsigned short* normb = (unsigned short*)(ws + 190316544);
  unsigned short* yb    = normb;
  char* S = ws + 253755392;
  float* st_vec = (float*)(S);
  float* bn_vec = (float*)(S + 262144);
  float* gbn    = (float*)(S + 786432);
  float* gst    = (float*)(S + 786944);
  unsigned short* W1b  = (unsigned short*)(S + 791040);
  unsigned short* W2b  = (unsigned short*)(S + 1315328);
  unsigned short* Wc1  = (unsigned short*)(S + 1839616);
  unsigned short* Wc2  = (unsigned short*)(S + 1913344);
  unsigned short* bnWb = (unsigned short*)(S + 1987072);

  hipMemsetAsync(st_vec, 0, 1024*64*sizeof(float), stream);
  k_gauss<<<1, 256, 0, stream>>>(gbn, gst);
  k_trans<<<256, 256, 0, stream>>>(pw1_w, pw2_w, bn_w, st1_w, st2_w, W1b, W2b, bnWb, Wc1, Wc2);

  // st path: gather (A = v_win), fused conv1+conv2 (band=16, round-11 config)
  k_stg<<<2048, 256, 0, stream>>>(vis, pos, v_win);
  k_stconv<<<dim3(1024, 2), 512, 0, stream>>>(v_win, Wc1, st1_b, Wc2, st2_b, gst, st_vec);

  // bn pre (v_win dead: dcob -> A); 128-ch blocks
  k_bnpre<<<dim3(1024, 2), 512, 0, stream>>>(bott, pos, dw_w, dw_b, x_bf, dcob);
  k_ln<<<30976, 256, 0, stream>>>(dcob, ln_g, ln_b, normb);

  // MLP: 2 M-chunks of two GEMMs (dcob dead; A = Hq full; yb overlays consumed normb)
  for (int q = 0; q < 2; ++q){
    size_t ro = (size_t)q * MQ2;
    k_gemm1<<<3872, 256, 0, stream>>>(normb + ro*256, W1b, pw1_b, Hq);
    k_gemm2<<<1936, 256, 0, stream>>>(Hq, W2b, pw2_b, lsg, x_bf + ro*256, yb + ro*256);
  }
  k_bnvec<<<1024, 256, 0, stream>>>(yb, bnWb, bn_b, gbn, bn_vec);

  // head
  k_head<<<256, 256, 0, stream>>>(bn_vec, st_vec, tr1_w, tr1_b, tr2_w, tr2_b,
                                  md_w, md_b, initm, (float*)d_out);
}

// Round 17
// 1138.805 us; speedup vs baseline: 1.3273x; 1.0689x over previous
//
#include <hip/hip_runtime.h>
#include <math.h>

// ---------------- constants ----------------
#define N_SRC 1024
#define VHW 1024
#define FHW 256
#define MQ2 61952           // M-chunk rows (123904/2) = 484 * 128

typedef __attribute__((ext_vector_type(8))) short short8;
typedef __attribute__((ext_vector_type(4))) float f32x4;

#define MFMA_B16(a,b,c) __builtin_amdgcn_mfma_f32_16x16x32_bf16((a),(b),(c),0,0,0)

__device__ __forceinline__ float gelu_f(float x){
  return 0.5f * x * (1.0f + erff(x * 0.70710678118654752440f));
}
__device__ __forceinline__ unsigned short f2bf(float f){
  union { float f; unsigned u; } x; x.f = f;
  unsigned r = x.u + 0x7fffu + ((x.u >> 16) & 1u);
  return (unsigned short)(r >> 16);
}
__device__ __forceinline__ float bf2f(unsigned short h){
  union { unsigned u; float f; } x; x.u = ((unsigned)h) << 16;
  return x.f;
}

// ---------------- gaussian tables ----------------
__global__ void k_gauss(float* __restrict__ gbn, float* __restrict__ gst){
  __shared__ double red[256];
  int t = threadIdx.x;
  {
    double v = 0.0;
    if (t < 121){
      int r = t / 11, c = t % 11;
      double y = -1.0 + 2.0 * (double)r / 10.0;
      double x = -1.0 + 2.0 * (double)c / 10.0;
      v = exp(-(x*x + y*y) / (2.0 * 0.4 * 0.4));
    }
    red[t] = v; __syncthreads();
    for (int s = 128; s > 0; s >>= 1){ if (t < s) red[t] += red[t+s]; __syncthreads(); }
    double sum = red[0];
    __syncthreads();
    if (t < 121) gbn[t] = (float)(v / sum);
    __syncthreads();
  }
  {
    double vals[4]; double loc = 0.0;
    #pragma unroll
    for (int i = 0; i < 4; ++i){
      int j = t + 256*i;
      double v = 0.0;
      if (j < 961){
        int r = j / 31, c = j % 31;
        double y = -1.0 + 2.0 * (double)r / 30.0;
        double x = -1.0 + 2.0 * (double)c / 30.0;
        v = exp(-(x*x + y*y) / (2.0 * 0.4 * 0.4));
      }
      vals[i] = v; loc += v;
    }
    red[t] = loc; __syncthreads();
    for (int s = 128; s > 0; s >>= 1){ if (t < s) red[t] += red[t+s]; __syncthreads(); }
    double sum = red[0];
    __syncthreads();
    #pragma unroll
    for (int i = 0; i < 4; ++i){
      int j = t + 256*i;
      if (j < 961) gst[j] = (float)(vals[i] / sum);
    }
  }
}

// ---------------- weight conversion ----------------
__global__ void k_trans(const float* __restrict__ pw1_w, const float* __restrict__ pw2_w,
                        const float* __restrict__ bn_w,
                        const float* __restrict__ st1_w, const float* __restrict__ st2_w,
                        unsigned short* __restrict__ W1b, unsigned short* __restrict__ W2b,
                        unsigned short* __restrict__ bnWb,
                        unsigned short* __restrict__ Wc1, unsigned short* __restrict__ Wc2){
  int stride = gridDim.x * blockDim.x;
  int i0 = blockIdx.x * blockDim.x + threadIdx.x;
  for (int e = i0; e < 256*1024; e += stride) W1b[e] = f2bf(pw1_w[e]);
  for (int e = i0; e < 256*1024; e += stride) W2b[e] = f2bf(pw2_w[e]);
  for (int e = i0; e < 128*256; e += stride) bnWb[e] = f2bf(bn_w[e]);
  for (int e = i0; e < 64*576; e += stride){
    int co = e / 576, r = e % 576, d = r >> 6, ci = r & 63;
    Wc1[e] = f2bf(st1_w[(co*64 + ci)*9 + d]);
    Wc2[e] = f2bf(st2_w[(co*64 + ci)*9 + d]);
  }
}

// =======================================================================
// st path (split, plane-major everywhere):
//   k_stg  : gather vis -> v_win bf16 [8cg][n*961][8]
//   k_stc1 : conv1+gelu -> g1 bf16 [8cg][n*961][8] (reg acc, LDS-staged
//            coalesced 16B stores)
//   k_stc2 : conv2+gelu+gaussian reduce -> st_vec
// =======================================================================

__global__ __launch_bounds__(256) void k_stg(
    const float* __restrict__ vis, const float* __restrict__ pos,
    unsigned short* __restrict__ v_win)
{
  int b = blockIdx.x;
  int n = b >> 1, h = b & 1;
  float px = pos[2*n], py = pos[2*n + 1];
  int e0 = h * 3844;                      // 961*8/2
  for (int e = e0 + threadIdx.x; e < e0 + 3844; e += 256){
    int cg = e / 961, p = e - cg*961;
    int r = p / 31, c = p - r*31;
    float xsf = fminf(fmaxf(px + (float)(c - 15), 0.f), 1023.f);
    float ysf = fminf(fmaxf(py + (float)(r - 15), 0.f), 1023.f);
    int x0 = min((int)xsf, 1022);
    int y0 = min((int)ysf, 1022);
    float wx = xsf - (float)x0, wy = ysf - (float)y0;
    float w00 = (1.f-wy)*(1.f-wx), w01 = (1.f-wy)*wx;
    float w10 = wy*(1.f-wx),       w11 = wy*wx;
    size_t off = (size_t)y0*VHW + x0;
    const float* bp = vis + (size_t)(cg*8)*(VHW*VHW) + off;
    short8 v;
    #pragma unroll
    for (int i = 0; i < 8; ++i){
      const float* bb = bp + (size_t)i*(VHW*VHW);
      v[i] = (short)f2bf(bb[0]*w00 + bb[1]*w01 + bb[VHW]*w10 + bb[VHW+1]*w11);
    }
    *(short8*)&v_win[((size_t)cg*(1024*961) + (size_t)n*961 + p)*8] = v;
  }
}

// granule-major conv, single B array (16 co per wave); NP = granule stride
template<int NP>
__device__ __forceinline__ void conv_tiles_g1(
    const unsigned short* __restrict__ in_t, const short8* B0,
    int pb0, int pb1, int lk, f32x4& a00, f32x4& a10)
{
  const unsigned short* a0p = in_t + (lk*NP + pb0)*8;
  const unsigned short* a1p = in_t + (lk*NP + pb1)*8;
  #pragma unroll
  for (int ks = 0; ks < 18; ++ks){
    const int d = ks >> 1;
    const int dy = d / 3, dx = d - dy*3;
    const int off = (((ks & 1) ? 4*NP : 0) + dy*33 + dx) * 8;
    short8 A0 = *(const short8*)&a0p[off];
    short8 A1 = *(const short8*)&a1p[off];
    a00 = MFMA_B16(A0, B0[ks], a00);
    a10 = MFMA_B16(A1, B0[ks], a10);
  }
}

#define SB    8     // band rows
#define NPV   330   // input tile: 10 rows x 33 (stride 330 % 8 == 2, conflict-free)
#define NPO_S 250   // out-buffer granule stride (250 % 8 == 2)

// conv1: v_win -> g1 (plane-major), per (n, band of 8 rows)
__global__ __launch_bounds__(512, 4) void k_stc1(
    const unsigned short* __restrict__ v_win,
    const unsigned short* __restrict__ Wc1, const float* __restrict__ st1_b,
    unsigned short* __restrict__ g1)
{
  __shared__ __align__(16) unsigned short As[NPV*64];    // 42,240 B
  __shared__ __align__(16) unsigned short Os[NPO_S*64];  // 32,000 B
  int n = blockIdx.x, band = blockIdx.y;
  int t = threadIdx.x;
  int w = t >> 6, l = t & 63, lr = l & 15, lk = l >> 4;
  int co0 = (w & 3) * 16;        // 4-way co split
  int mh = w >> 2;               // 2-way m split
  int y0 = band*SB;
  int rows_out = min(SB, 31 - y0);
  int ybaseV = y0 - 1;

  // stage As (granule-major, zero-pad halo); consecutive idx -> consecutive p
  for (int idx = t; idx < NPV*8; idx += 512){
    int cg = idx / NPV, p = idx - cg*NPV;
    int gr = p / 33, gc = p - gr*33;
    int yy = ybaseV + gr, xx = gc - 1;
    short8 v = {0,0,0,0,0,0,0,0};
    if (yy >= 0 && yy < 31 && xx >= 0 && xx < 31)
      v = *(const short8*)&v_win[((size_t)cg*(1024*961) + (size_t)n*961 + yy*31 + xx)*8];
    *(short8*)&As[(cg*NPV + p)*8] = v;
  }
  __syncthreads();

  int npos = rows_out * 31;
  int ntiles = (npos + 15) >> 4;
  {
    short8 B0[18];
    #pragma unroll
    for (int ks = 0; ks < 18; ++ks)
      B0[ks] = *(const short8*)&Wc1[(co0 + lr)*576 + ks*32 + lk*8];
    float bc0 = st1_b[co0 + lr];
    int c0 = co0 + lr;
    int per = (ntiles + 1) >> 1;
    int mstart = mh * per;
    int mend = min(mstart + per, ntiles);

    for (int mt = mstart; mt < mend; mt += 2){
      int s0 = min(mt*16 + lr, npos - 1);
      int s1 = min(mt*16 + 16 + lr, npos - 1);
      int ly0 = s0 / 31, x0p = s0 - ly0*31;
      int ly1 = s1 / 31, x1p = s1 - ly1*31;
      int pb0 = ly0*33 + x0p, pb1 = ly1*33 + x1p;
      f32x4 a00 = {0,0,0,0}, a10 = {0,0,0,0};
      conv_tiles_g1<NPV>(As, B0, pb0, pb1, lk, a00, a10);
      #pragma unroll
      for (int i = 0; i < 4; ++i){
        int spo = mt*16 + lk*4 + i;
        if (spo < npos)
          Os[((c0 >> 3)*NPO_S + spo)*8 + (c0 & 7)] = f2bf(gelu_f(a00[i] + bc0));
        int sp1 = spo + 16;
        if (sp1 < npos && mt + 1 < mend)
          Os[((c0 >> 3)*NPO_S + sp1)*8 + (c0 & 7)] = f2bf(gelu_f(a10[i] + bc0));
      }
    }
  }
  __syncthreads();

  // coalesced copy-out: Os -> g1 (positions are row-major within band)
  size_t gbase = (size_t)n*961 + y0*31;
  for (int idx = t; idx < npos*8; idx += 512){
    int cg = idx / npos, po = idx - cg*npos;
    *(short8*)&g1[((size_t)cg*(1024*961) + gbase + po)*8] =
        *(const short8*)&Os[(cg*NPO_S + po)*8];
  }
}

// conv2 + gaussian reduce: g1 -> st_vec, per (n, band of 8 rows)
__global__ __launch_bounds__(512, 4) void k_stc2(
    const unsigned short* __restrict__ g1, const float* __restrict__ gst,
    const unsigned short* __restrict__ Wc2, const float* __restrict__ st2_b,
    float* __restrict__ st_vec)
{
  __shared__ __align__(16) unsigned short Bs[NPV*64];    // 42,240 B
  int n = blockIdx.x, band = blockIdx.y;
  int t = threadIdx.x;
  int w = t >> 6, l = t & 63, lr = l & 15, lk = l >> 4;
  int co0 = (w & 3) * 16;
  int mh = w >> 2;
  int y0 = band*SB;
  int rows_out = min(SB, 31 - y0);
  int ybaseG = y0 - 1;

  // stage Bs from g1 (plane-major, contiguous row runs), zero-pad halo
  for (int idx = t; idx < NPV*8; idx += 512){
    int cg = idx / NPV, p = idx - cg*NPV;
    int gr = p / 33, gc = p - gr*33;
    int yy = ybaseG + gr, xx = gc - 1;
    short8 v = {0,0,0,0,0,0,0,0};
    if (yy >= 0 && yy < 31 && xx >= 0 && xx < 31)
      v = *(const short8*)&g1[((size_t)cg*(1024*961) + (size_t)n*961 + yy*31 + xx)*8];
    *(short8*)&Bs[(cg*NPV + p)*8] = v;
  }
  __syncthreads();

  {
    short8 B0[18];
    #pragma unroll
    for (int ks = 0; ks < 18; ++ks)
      B0[ks] = *(const short8*)&Wc2[(co0 + lr)*576 + ks*32 + lk*8];
    int npos = rows_out * 31;
    int ntiles = (npos + 15) >> 4;
    int per = (ntiles + 1) >> 1;
    int mstart = mh * per;
    int mend = min(mstart + per, ntiles);
    float bc0 = st2_b[co0 + lr];
    float vacc0 = 0.f;

    for (int mt = mstart; mt < mend; mt += 2){
      int s0 = min(mt*16 + lr, npos - 1);
      int s1 = min(mt*16 + 16 + lr, npos - 1);
      int ly0 = s0 / 31, x0p = s0 - ly0*31;
      int ly1 = s1 / 31, x1p = s1 - ly1*31;
      int pb0 = ly0*33 + x0p, pb1 = ly1*33 + x1p;
      f32x4 a00 = {0,0,0,0}, a10 = {0,0,0,0};
      conv_tiles_g1<NPV>(Bs, B0, pb0, pb1, lk, a00, a10);
      #pragma unroll
      for (int i = 0; i < 4; ++i){
        int spo = mt*16 + lk*4 + i;
        if (spo < npos){
          int ly = spo / 31, xx = spo - ly*31;
          float wt = gst[(y0 + ly)*31 + xx];
          vacc0 += wt * gelu_f(a00[i] + bc0);
        }
        int sp1 = spo + 16;
        if (sp1 < npos && mt + 1 < mend){
          int ly = sp1 / 31, xx = sp1 - ly*31;
          float wt = gst[(y0 + ly)*31 + xx];
          vacc0 += wt * gelu_f(a10[i] + bc0);
        }
      }
    }
    vacc0 += __shfl_xor(vacc0, 16); vacc0 += __shfl_xor(vacc0, 32);
    if (lk == 0)
      atomicAdd(&st_vec[n*64 + co0 + lr], vacc0);
  }
}

// ---------------- bn path: fused gather + depthwise 7x7, 128-ch blocks ----------
__global__ __launch_bounds__(512, 4) void k_bnpre(
  const float* __restrict__ bott, const float* __restrict__ pos,
  const float* __restrict__ dw_w, const float* __restrict__ dw_b,
  unsigned short* __restrict__ x_bf, unsigned short* __restrict__ dcob)
{
  __shared__ float xt[128*123];
  __shared__ float wt4[121*4];
  __shared__ int   wo[121];
  int n = blockIdx.x, ch0 = blockIdx.y * 128;
  int t = threadIdx.x;
  float pbx = (pos[2*n]   + 0.5f)*0.25f - 0.5f;
  float pby = (pos[2*n+1] + 0.5f)*0.25f - 0.5f;

  if (t < 121){
    int r = t / 11, c = t - r*11;
    float xsf = fminf(fmaxf(pbx + (float)(c-5), 0.f), 255.f);
    float ysf = fminf(fmaxf(pby + (float)(r-5), 0.f), 255.f);
    int x0 = min((int)xsf, 254);
    int y0 = min((int)ysf, 254);
    float wx = xsf - (float)x0, wy = ysf - (float)y0;
    wo[t] = y0*FHW + x0;
    wt4[t*4+0] = (1.f-wy)*(1.f-wx);
    wt4[t*4+1] = (1.f-wy)*wx;
    wt4[t*4+2] = wy*(1.f-wx);
    wt4[t*4+3] = wy*wx;
  }
  __syncthreads();

  for (int e = t; e < 128*121; e += 512){
    int ch = e / 121, p = e - ch*121;
    const float* b = bott + (size_t)(ch0 + ch)*(FHW*FHW) + wo[p];
    float4 w = *(const float4*)&wt4[p*4];
    xt[ch*123 + p] = b[0]*w.x + b[1]*w.y + b[FHW]*w.z + b[FHW+1]*w.w;
  }
  __syncthreads();

  for (int e = t; e < 121*64; e += 512){
    int row = e >> 6, cp = (e & 63) << 1;
    float v0 = xt[cp*123 + row], v1 = xt[(cp+1)*123 + row];
    unsigned pk = (unsigned)f2bf(v0) | ((unsigned)f2bf(v1) << 16);
    *(unsigned*)&x_bf[(((size_t)n*121 + row) << 8) + ch0 + cp] = pk;
  }

  int ch = t & 127, part = t >> 7;
  float w[49];
  #pragma unroll
  for (int k = 0; k < 49; ++k) w[k] = dw_w[(ch0 + ch)*49 + k];
  float bias = dw_b[ch0 + ch];
  const float* xc = &xt[ch*123];
  for (int sp = part; sp < 121; sp += 4){
    int r = sp / 11, c = sp - r*11;
    float a = bias;
    #pragma unroll
    for (int dy = 0; dy < 7; ++dy){
      int ry = r + dy - 3;
      bool okr = (ry >= 0) && (ry < 11);
      #pragma unroll
      for (int dx = 0; dx < 7; ++dx){
        int cx = c + dx - 3;
        float xv = (okr && cx >= 0 && cx < 11) ? xc[ry*11 + cx] : 0.f;
        a = fmaf(xv, w[dy*7 + dx], a);
      }
    }
    dcob[(((size_t)n*121 + sp) << 8) + ch0 + ch] = f2bf(a);
  }
}

// ---------------- bn path: layernorm bf16 -> bf16 ----------------
__global__ __launch_bounds__(256) void k_ln(
  const unsigned short* __restrict__ dcob, const float* __restrict__ ln_g, const float* __restrict__ ln_b,
  unsigned short* __restrict__ normb)
{
  int m = blockIdx.x*4 + (threadIdx.x >> 6);
  int lane = threadIdx.x & 63;
  ushort4 raw = *(const ushort4*)&dcob[(size_t)m*256 + lane*4];
  float4 v = { bf2f(raw.x), bf2f(raw.y), bf2f(raw.z), bf2f(raw.w) };
  float s  = v.x+v.y+v.z+v.w;
  float ss = v.x*v.x + v.y*v.y + v.z*v.z + v.w*v.w;
  #pragma unroll
  for (int off = 32; off; off >>= 1){ s += __shfl_xor(s, off); ss += __shfl_xor(ss, off); }
  float mu  = s * 0.00390625f;
  float var = ss * 0.00390625f - mu*mu;
  float rstd = 1.0f / sqrtf(var + 1e-6f);
  float4 g = *(const float4*)&ln_g[lane*4];
  float4 b = *(const float4*)&ln_b[lane*4];
  ushort4 o;
  o.x = f2bf((v.x-mu)*rstd*g.x + b.x);
  o.y = f2bf((v.y-mu)*rstd*g.y + b.y);
  o.z = f2bf((v.z-mu)*rstd*g.z + b.z);
  o.w = f2bf((v.w-mu)*rstd*g.w + b.w);
  *(ushort4*)&normb[(size_t)m*256 + lane*4] = o;
}

// =======================================================================
// MLP as two m97-style GEMMs over M-chunks of 61952 rows (2 chunks).
// =======================================================================

__global__ __launch_bounds__(256, 3) void k_gemm1(
  const unsigned short* __restrict__ A, const unsigned short* __restrict__ B,
  const float* __restrict__ b1, unsigned short* __restrict__ H)
{
  __shared__ __align__(16) unsigned short sm[16384];
  unsigned short* As = sm;
  unsigned short* Bs = sm + 8192;
  int t = threadIdx.x, lane = t & 63, w = t >> 6;
  int lr = lane & 15, lk = lane >> 4;
  int p = blockIdx.x;
  int L = (p & 7) * 484 + (p >> 3);
  int m0 = (L >> 3) * 128, n0 = (L & 7) * 128;

  f32x4 acc[2][8];
  #pragma unroll
  for (int i = 0; i < 2; ++i)
    #pragma unroll
    for (int j = 0; j < 8; ++j) acc[i][j] = (f32x4){0,0,0,0};

  for (int ks = 0; ks < 4; ++ks){
    if (ks) __syncthreads();
    #pragma unroll
    for (int it = 0; it < 4; ++it){
      int j = t + it*256;
      int r = j >> 3, c = j & 7;
      int k8 = c ^ (r & 7);
      *(short8*)&As[j*8] = *(const short8*)&A[(size_t)(m0 + r)*256 + ks*64 + k8*8];
      *(short8*)&Bs[j*8] = *(const short8*)&B[(size_t)(n0 + r)*256 + ks*64 + k8*8];
    }
    __syncthreads();
    #pragma unroll
    for (int kk = 0; kk < 2; ++kk){
      int k8a = kk*4 + lk;
      short8 af[2];
      #pragma unroll
      for (int i = 0; i < 2; ++i){
        int ra = w*32 + i*16 + lr;
        af[i] = *(const short8*)&As[(ra*8 + (k8a ^ (ra & 7)))*8];
      }
      #pragma unroll
      for (int j = 0; j < 8; ++j){
        int rb = j*16 + lr;
        short8 bf = *(const short8*)&Bs[(rb*8 + (k8a ^ (rb & 7)))*8];
        acc[0][j] = MFMA_B16(af[0], bf, acc[0][j]);
        acc[1][j] = MFMA_B16(af[1], bf, acc[1][j]);
      }
    }
  }
  __syncthreads();
  #pragma unroll
  for (int i = 0; i < 2; ++i)
    #pragma unroll
    for (int j = 0; j < 8; ++j){
      int col = j*16 + lr;
      float bb = b1[n0 + col];
      #pragma unroll
      for (int q = 0; q < 4; ++q){
        int row = w*32 + i*16 + lk*4 + q;
        sm[row*128 + col] = f2bf(gelu_f(acc[i][j][q] + bb));
      }
    }
  __syncthreads();
  #pragma unroll
  for (int it = 0; it < 8; ++it){
    int e = t + it*256;
    int row = e >> 4, c8 = e & 15;
    *(short8*)&H[(size_t)(m0 + row)*1024 + n0 + c8*8] = *(const short8*)&sm[row*128 + c8*8];
  }
}

__global__ __launch_bounds__(256, 4) void k_gemm2(
  const unsigned short* __restrict__ A, const unsigned short* __restrict__ B,
  const float* __restrict__ b2v, const float* __restrict__ lsg,
  const unsigned short* __restrict__ xres, unsigned short* __restrict__ Y)
{
  __shared__ __align__(16) unsigned short sm[16384];
  unsigned short* As = sm;
  unsigned short* Bs = sm + 8192;
  int t = threadIdx.x, lane = t & 63, w = t >> 6;
  int lr = lane & 15, lk = lane >> 4;
  int p = blockIdx.x;
  int L = (p & 7) * 242 + (p >> 3);
  int m0 = (L >> 2) * 128, n0 = (L & 3) * 64;

  f32x4 acc[2][4];
  #pragma unroll
  for (int i = 0; i < 2; ++i)
    #pragma unroll
    for (int j = 0; j < 4; ++j) acc[i][j] = (f32x4){0,0,0,0};

  for (int ks = 0; ks < 16; ++ks){
    if (ks) __syncthreads();
    #pragma unroll
    for (int it = 0; it < 4; ++it){
      int j = t + it*256;
      int r = j >> 3, c = j & 7;
      int k8 = c ^ (r & 7);
      *(short8*)&As[j*8] = *(const short8*)&A[(size_t)(m0 + r)*1024 + ks*64 + k8*8];
    }
    #pragma unroll
    for (int it = 0; it < 2; ++it){
      int j = t + it*256;
      int r = j >> 3, c = j & 7;
      int k8 = c ^ (r & 7);
      *(short8*)&Bs[j*8] = *(const short8*)&B[(size_t)(n0 + r)*1024 + ks*64 + k8*8];
    }
    __syncthreads();
    #pragma unroll
    for (int kk = 0; kk < 2; ++kk){
      int k8a = kk*4 + lk;
      short8 af[2];
      #pragma unroll
      for (int i = 0; i < 2; ++i){
        int ra = w*32 + i*16 + lr;
        af[i] = *(const short8*)&As[(ra*8 + (k8a ^ (ra & 7)))*8];
      }
      #pragma unroll
      for (int j = 0; j < 4; ++j){
        int rb = j*16 + lr;
        short8 bf = *(const short8*)&Bs[(rb*8 + (k8a ^ (rb & 7)))*8];
        acc[0][j] = MFMA_B16(af[0], bf, acc[0][j]);
        acc[1][j] = MFMA_B16(af[1], bf, acc[1][j]);
      }
    }
  }
  __syncthreads();
  float* Cs = (float*)sm;
  #pragma unroll
  for (int i = 0; i < 2; ++i)
    #pragma unroll
    for (int j = 0; j < 4; ++j){
      int col = j*16 + lr;
      #pragma unroll
      for (int q = 0; q < 4; ++q){
        int row = w*32 + i*16 + lk*4 + q;
        Cs[row*64 + col] = acc[i][j][q];
      }
    }
  __syncthreads();
  #pragma unroll
  for (int it = 0; it < 8; ++it){
    int e4 = t + it*256;
    int row = e4 >> 4, c4 = (e4 & 15) * 4;
    float4 cv = *(const float4*)&Cs[row*64 + c4];
    size_t grow = (size_t)(m0 + row);
    ushort4 xr = *(const ushort4*)&xres[grow*256 + n0 + c4];
    float4 bb = *(const float4*)&b2v[n0 + c4];
    float4 gm = *(const float4*)&lsg[n0 + c4];
    ushort4 o;
    o.x = f2bf(fmaf(cv.x + bb.x, gm.x, bf2f(xr.x)));
    o.y = f2bf(fmaf(cv.y + bb.y, gm.y, bf2f(xr.y)));
    o.z = f2bf(fmaf(cv.z + bb.z, gm.z, bf2f(xr.z)));
    o.w = f2bf(fmaf(cv.w + bb.w, gm.w, bf2f(xr.w)));
    *(ushort4*)&Y[grow*256 + n0 + c4] = o;
  }
}

// ---------------- bn path: 1x1 conv 256->128 (MFMA) + gelu + gaussian reduce ----------
__global__ __launch_bounds__(256) void k_bnvec(
  const unsigned short* __restrict__ yb, const unsigned short* __restrict__ bnWb,
  const float* __restrict__ bn_b, const float* __restrict__ gbn, float* __restrict__ bn_vec)
{
  int n = blockIdx.x, t = threadIdx.x;
  int w = t >> 6, l = t & 63, lr = l & 15, lk = l >> 4;
  f32x4 acc[8][2];
  #pragma unroll
  for (int mt = 0; mt < 8; ++mt){ acc[mt][0] = (f32x4){0,0,0,0}; acc[mt][1] = (f32x4){0,0,0,0}; }

  #pragma unroll
  for (int ks = 0; ks < 8; ++ks){
    short8 b0 = *(const short8*)&bnWb[(size_t)(w*32 + lr)*256 + ks*32 + lk*8];
    short8 b1 = *(const short8*)&bnWb[(size_t)(w*32 + 16 + lr)*256 + ks*32 + lk*8];
    #pragma unroll
    for (int mt = 0; mt < 8; ++mt){
      int row = min(mt*16 + lr, 120);
      short8 a = *(const short8*)&yb[((size_t)n*121 + row)*256 + ks*32 + lk*8];
      acc[mt][0] = MFMA_B16(a, b0, acc[mt][0]);
      acc[mt][1] = MFMA_B16(a, b1, acc[mt][1]);
    }
  }

  float s0 = 0.f, s1 = 0.f;
  float bb0 = bn_b[w*32 + lr], bb1 = bn_b[w*32 + 16 + lr];
  #pragma unroll
  for (int mt = 0; mt < 8; ++mt)
    #pragma unroll
    for (int i = 0; i < 4; ++i){
      int row = mt*16 + lk*4 + i;
      if (row < 121){
        float g = gbn[row];
        s0 += g * gelu_f(acc[mt][0][i] + bb0);
        s1 += g * gelu_f(acc[mt][1][i] + bb1);
      }
    }
  s0 += __shfl_xor(s0, 16); s0 += __shfl_xor(s0, 32);
  s1 += __shfl_xor(s1, 16); s1 += __shfl_xor(s1, 32);
  if (lk == 0){
    bn_vec[n*128 + w*32 + lr] = s0;
    bn_vec[n*128 + w*32 + 16 + lr] = s1;
  }
}

// ---------------- head: 4 n per block ----------------
__global__ __launch_bounds__(256) void k_head(
  const float* __restrict__ bn_vec, const float* __restrict__ st_vec,
  const float* __restrict__ tr1_w, const float* __restrict__ tr1_b,
  const float* __restrict__ tr2_w, const float* __restrict__ tr2_b,
  const float* __restrict__ md_w, const float* __restrict__ md_b,
  const float* __restrict__ init_m,
  float* __restrict__ out)
{
  __shared__ float feat4[4*192];
  __shared__ float h14[4*256];
  __shared__ float h24[4*256];
  __shared__ float dlt4[4*961];
  __shared__ float yv4[4*961];
  int t = threadIdx.x;
  int n0 = blockIdx.x * 4;
  float* morph_out = out;
  float* delta_out = out + 984064;
  float* feat_out  = out + 1968128;

  for (int e = t; e < 4*192; e += 256){
    int ni = e / 192, j = e - ni*192;
    float v = (j < 128) ? bn_vec[(n0+ni)*128 + j] : st_vec[(n0+ni)*64 + j - 128];
    feat4[e] = v;
    feat_out[(size_t)(n0+ni)*192 + j] = v;
  }
  __syncthreads();
  {
    float a0 = tr1_b[t], a1 = a0, a2 = a0, a3 = a0;
    const float* wr = &tr1_w[t*192];
    for (int k = 0; k < 192; ++k){
      float wk = wr[k];
      a0 = fmaf(feat4[k],       wk, a0);
      a1 = fmaf(feat4[192 + k], wk, a1);
      a2 = fmaf(feat4[384 + k], wk, a2);
      a3 = fmaf(feat4[576 + k], wk, a3);
    }
    h14[t] = gelu_f(a0); h14[256 + t] = gelu_f(a1);
    h14[512 + t] = gelu_f(a2); h14[768 + t] = gelu_f(a3);
  }
  __syncthreads();
  {
    float a0 = tr2_b[t], a1 = a0, a2 = a0, a3 = a0;
    const float* wr = &tr2_w[t*256];
    for (int k = 0; k < 256; ++k){
      float wk = wr[k];
      a0 = fmaf(h14[k],       wk, a0);
      a1 = fmaf(h14[256 + k], wk, a1);
      a2 = fmaf(h14[512 + k], wk, a2);
      a3 = fmaf(h14[768 + k], wk, a3);
    }
    h24[t] = gelu_f(a0); h24[256 + t] = gelu_f(a1);
    h24[512 + t] = gelu_f(a2); h24[768 + t] = gelu_f(a3);
  }
  __syncthreads();
  for (int j = t; j < 961; j += 256){
    float b = md_b[j];
    float a0 = b, a1 = b, a2 = b, a3 = b;
    const float* wr = &md_w[(size_t)j*256];
    for (int k = 0; k < 256; ++k){
      float wk = wr[k];
      a0 = fmaf(h24[k],       wk, a0);
      a1 = fmaf(h24[256 + k], wk, a1);
      a2 = fmaf(h24[512 + k], wk, a2);
      a3 = fmaf(h24[768 + k], wk, a3);
    }
    float d0 = tanhf(a0), d1 = tanhf(a1), d2 = tanhf(a2), d3 = tanhf(a3);
    dlt4[j] = d0; dlt4[961 + j] = d1; dlt4[1922 + j] = d2; dlt4[2883 + j] = d3;
    delta_out[(size_t)(n0+0)*961 + j] = d0;
    delta_out[(size_t)(n0+1)*961 + j] = d1;
    delta_out[(size_t)(n0+2)*961 + j] = d2;
    delta_out[(size_t)(n0+3)*961 + j] = d3;
  }
  __syncthreads();

  int g = t >> 6, l64 = t & 63;
  int n = n0 + g;
  const float* im = &init_m[(size_t)n*961];
  float loc = 0.f;
  for (int j = l64; j < 961; j += 64) loc += fmaxf(im[j], 0.f);
  #pragma unroll
  for (int off = 32; off; off >>= 1) loc += __shfl_xor(loc, off);
  float s0 = loc + 1e-8f;
  float loc2 = 0.f;
  for (int j = l64; j < 961; j += 64){
    float imn = fmaxf(im[j], 0.f) / s0;
    float x = fmaxf(imn, 1e-8f);
    float base = x + logf(-expm1f(-x));
    float z = base + 1.5f * dlt4[g*961 + j];
    float y = fmaxf(z, 0.f) + log1pf(expf(-fabsf(z)));
    yv4[g*961 + j] = y;
    loc2 += y;
  }
  #pragma unroll
  for (int off = 32; off; off >>= 1) loc2 += __shfl_xor(loc2, off);
  float s1 = loc2 + 1e-8f;
  for (int j = l64; j < 961; j += 64)
    morph_out[(size_t)n*961 + j] = yv4[g*961 + j] / s1;
}

// ---------------- launch ----------------
extern "C" void kernel_launch(void* const* d_in, const int* in_sizes, int n_in,
                              void* d_out, int out_size, void* d_ws, size_t ws_size,
                              hipStream_t stream)
{
  const float* bott = (const float*)d_in[0];
  const float* vis  = (const float*)d_in[1];
  const float* pos  = (const float*)d_in[2];
  const float* initm= (const float*)d_in[3];
  const float* dw_w = (const float*)d_in[4];
  const float* dw_b = (const float*)d_in[5];
  const float* ln_g = (const float*)d_in[6];
  const float* ln_b = (const float*)d_in[7];
  const float* pw1_w= (const float*)d_in[8];
  const float* pw1_b= (const float*)d_in[9];
  const float* pw2_w= (const float*)d_in[10];
  const float* pw2_b= (const float*)d_in[11];
  const float* lsg  = (const float*)d_in[12];
  const float* bn_w = (const float*)d_in[13];
  const float* bn_b = (const float*)d_in[14];
  const float* st1_w= (const float*)d_in[15];
  const float* st1_b= (const float*)d_in[16];
  const float* st2_w= (const float*)d_in[17];
  const float* st2_b= (const float*)d_in[18];
  const float* tr1_w= (const float*)d_in[19];
  const float* tr1_b= (const float*)d_in[20];
  const float* tr2_w= (const float*)d_in[21];
  const float* tr2_b= (const float*)d_in[22];
  const float* md_w = (const float*)d_in[23];
  const float* md_b = (const float*)d_in[24];

  char* ws = (char*)d_ws;
  // Region A (126.9MB): v_win (st path) -> dcob (bnpre) -> Hq (gemms)
  unsigned short* v_win = (unsigned short*)(ws);
  unsigned short* dcob  = (unsigned short*)(ws);
  unsigned short* Hq    = (unsigned short*)(ws);
  // Regions B+C (126.9MB): g1 (st path) -> x_bf | normb
  unsigned short* g1    = (unsigned short*)(ws + 126877696);
  unsigned short* x_bf  = (unsigned short*)(ws + 126877696);
  unsigned short* normb = (unsigned short*)(ws + 190316544);
  unsigned short* yb    = normb;   // chunk-serial overlay (rows consumed before overwrite)
  char* S = ws + 253755392;
  float* st_vec = (float*)(S);
  float* bn_vec = (float*)(S + 262144);
  float* gbn    = (float*)(S + 786432);
  float* gst    = (float*)(S + 786944);
  unsigned short* W1b  = (unsigned short*)(S + 791040);
  unsigned short* W2b  = (unsigned short*)(S + 1315328);
  unsigned short* Wc1  = (unsigned short*)(S + 1839616);
  unsigned short* Wc2  = (unsigned short*)(S + 1913344);
  unsigned short* bnWb = (unsigned short*)(S + 1987072);

  hipMemsetAsync(st_vec, 0, 1024*64*sizeof(float), stream);
  k_gauss<<<1, 256, 0, stream>>>(gbn, gst);
  k_trans<<<256, 256, 0, stream>>>(pw1_w, pw2_w, bn_w, st1_w, st2_w, W1b, W2b, bnWb, Wc1, Wc2);

  // st path: gather -> conv1 (g1 in B+C, plane-major) -> conv2+reduce
  k_stg<<<2048, 256, 0, stream>>>(vis, pos, v_win);
  k_stc1<<<dim3(1024, 4), 512, 0, stream>>>(v_win, Wc1, st1_b, g1);
  k_stc2<<<dim3(1024, 4), 512, 0, stream>>>(g1, gst, Wc2, st2_b, st_vec);

  // bn pre (v_win dead: dcob -> A; g1 dead: x_bf -> B)
  k_bnpre<<<dim3(1024, 2), 512, 0, stream>>>(bott, pos, dw_w, dw_b, x_bf, dcob);
  k_ln<<<30976, 256, 0, stream>>>(dcob, ln_g, ln_b, normb);

  // MLP: 2 M-chunks of two GEMMs (dcob dead; A = Hq full; yb overlays consumed normb)
  for (int q = 0; q < 2; ++q){
    size_t ro = (size_t)q * MQ2;
    k_gemm1<<<3872, 256, 0, stream>>>(normb + ro*256, W1b, pw1_b, Hq);
    k_gemm2<<<1936, 256, 0, stream>>>(Hq, W2b, pw2_b, lsg, x_bf + ro*256, yb + ro*256);
  }
  k_bnvec<<<1024, 256, 0, stream>>>(yb, bnWb, bn_b, gbn, bn_vec);

  // head
  k_head<<<256, 256, 0, stream>>>(bn_vec, st_vec, tr1_w, tr1_b, tr2_w, tr2_b,
                                  md_w, md_b, initm, (float*)d_out);
}